// Round 13
// baseline (466.630 us; speedup 1.0000x reference)
//
#include <hip/hip_runtime.h>
#include <stdint.h>

// AttentionBlock: GN -> QKV -> softmax(QK^T/sqrt(C)) V -> proj + residual
// B=4, C=256, H=W=64, N=4096, groups=8 (32 ch/group)
// All matmuls bf16 MFMA (fp32 accumulate). fp32 threshold 0.1 absmax.
//
// Round 13: 8-wave attn (512 thr) = 2 waves/SIMD with the round-11 32x32
// chunk-major dataflow. rg = w&1 (32 q-rows), quarter q = w>>1 sweeps 32 of
// 128 key tiles; single-buffered per-quarter K/V LDS (148 KB, 1 blk/CU).
// compute -> barrier -> stage -> barrier per iter. Static-max softmax ->
// 4-way merge is a pure sum (3-phase LDS tree over dead Kt/Vt).

#define B_ 4
#define C_ 256
#define N_ 4096
#define KVB 32

using bf16x8 = __attribute__((ext_vector_type(8))) __bf16;
using f32x4  = __attribute__((ext_vector_type(4))) float;
using f32x16 = __attribute__((ext_vector_type(16))) float;

__device__ __forceinline__ uint16_t f2bf(float f) {
    uint32_t u = __float_as_uint(f);
    u = (u + 0x7fffu + ((u >> 16) & 1u)) >> 16;   // RNE
    return (uint16_t)u;
}

__device__ __forceinline__ f32x4 mfma16(bf16x8 a, bf16x8 b, f32x4 c) {
    return __builtin_amdgcn_mfma_f32_16x16x32_bf16(a, b, c, 0, 0, 0);
}

__device__ __forceinline__ f32x16 mfma32(bf16x8 a, bf16x8 b, f32x16 c) {
    return __builtin_amdgcn_mfma_f32_32x32x16_bf16(a, b, c, 0, 0, 0);
}

__device__ __forceinline__ void gload16(const void* g, void* l) {
    __builtin_amdgcn_global_load_lds(
        (const __attribute__((address_space(1))) uint32_t*)g,
        (__attribute__((address_space(3))) uint32_t*)l, 16, 0, 0);
}

// ---------------- cast weights to bf16 ----------------
__global__ __launch_bounds__(256) void cast_weights(
        const float* __restrict__ qkvw, const float* __restrict__ projw,
        uint16_t* __restrict__ qkvwb, uint16_t* __restrict__ projwb) {
    int i = blockIdx.x * 256 + threadIdx.x;
    if (i < 768 * 256) qkvwb[i] = f2bf(qkvw[i]);
    int j = i - 768 * 256;
    if (j >= 0 && j < 256 * 256) projwb[j] = f2bf(projw[j]);
}

// ---------------- GroupNorm stats, two-stage ----------------
__global__ __launch_bounds__(256) void gn_stats1(const float* __restrict__ x,
                                                 float2* __restrict__ part) {
    int i = blockIdx.x;
    const float4* p = reinterpret_cast<const float4*>(x + (size_t)i * 4096);
    float s = 0.f, ss = 0.f;
    #pragma unroll
    for (int j = 0; j < 4; j++) {
        float4 v = p[threadIdx.x + j * 256];
        s  += v.x + v.y + v.z + v.w;
        ss += v.x*v.x + v.y*v.y + v.z*v.z + v.w*v.w;
    }
    #pragma unroll
    for (int d = 32; d > 0; d >>= 1) { s += __shfl_down(s, d); ss += __shfl_down(ss, d); }
    __shared__ float rs[4], rss[4];
    int wid = threadIdx.x >> 6;
    if ((threadIdx.x & 63) == 0) { rs[wid] = s; rss[wid] = ss; }
    __syncthreads();
    if (threadIdx.x == 0) {
        float2 o;
        o.x = rs[0] + rs[1] + rs[2] + rs[3];
        o.y = rss[0] + rss[1] + rss[2] + rss[3];
        part[i] = o;
    }
}
__global__ __launch_bounds__(1024) void gn_stats2(const float2* __restrict__ part,
                                                  float* __restrict__ stats) {
    int t = threadIdx.x;
    int g = t >> 5, j = t & 31;
    float2 v = part[g * 32 + j];
    float s = v.x, ss = v.y;
    #pragma unroll
    for (int d = 16; d > 0; d >>= 1) { s += __shfl_xor(s, d); ss += __shfl_xor(ss, d); }
    if (j == 0) {
        float mean = s / 131072.f;
        float var  = ss / 131072.f - mean * mean;
        stats[g * 2]     = mean;
        stats[g * 2 + 1] = rsqrtf(var + 1e-5f);
    }
}

// ---------------- GN apply + transpose: hT[b][n][c] bf16 ----------------
__global__ __launch_bounds__(256) void gn_apply(
        const float* __restrict__ x, const float* __restrict__ gnw,
        const float* __restrict__ gnb, const float* __restrict__ stats,
        uint16_t* __restrict__ hT) {
    int nb = blockIdx.x * 64, cb = blockIdx.y * 64, b = blockIdx.z;
    __shared__ uint16_t lds[64][64];          // [n][c]
    int t = threadIdx.x;
    int c_l = t >> 4;
    int n4  = (t & 15) * 4;
    #pragma unroll
    for (int i = 0; i < 4; i++) {
        int c = cb + c_l + 16 * i;
        int sg = b * 8 + (c >> 5);
        float mean = stats[sg * 2], rstd = stats[sg * 2 + 1];
        float sc = gnw[c] * rstd;
        float sh = gnb[c] - mean * sc;
        float4 v = *reinterpret_cast<const float4*>(x + ((size_t)b * C_ + c) * N_ + nb + n4);
        lds[n4 + 0][c_l + 16 * i] = f2bf(fmaf(v.x, sc, sh));
        lds[n4 + 1][c_l + 16 * i] = f2bf(fmaf(v.y, sc, sh));
        lds[n4 + 2][c_l + 16 * i] = f2bf(fmaf(v.z, sc, sh));
        lds[n4 + 3][c_l + 16 * i] = f2bf(fmaf(v.w, sc, sh));
    }
    __syncthreads();
    int n_l = t >> 2, c16 = (t & 3) * 16;
    uint4* dst = reinterpret_cast<uint4*>(hT + ((size_t)b * N_ + nb + n_l) * C_ + cb + c16);
    const uint4* sp = reinterpret_cast<const uint4*>(&lds[n_l][c16]);
    dst[0] = sp[0]; dst[1] = sp[1];
}

// ---------------- QKV GEMM ----------------
// q,k transposed [n][o]; q pre-scaled by 1/16 (softmax scale). v kept [o'][n].
__global__ __launch_bounds__(256) void qkv_gemm(
        const uint16_t* __restrict__ Wb, const float* __restrict__ qkvb,
        const uint16_t* __restrict__ hT, uint16_t* __restrict__ qT,
        uint16_t* __restrict__ kT, uint16_t* __restrict__ vO) {
    int nt = blockIdx.x, ot = blockIdx.y, b = blockIdx.z;
    int lane = threadIdx.x & 63, w = threadIdx.x >> 6;
    int l15 = lane & 15, g = lane >> 4;
    const uint16_t* hTb = hT + (size_t)b * N_ * C_;
    f32x4 z = {0.f, 0.f, 0.f, 0.f};
    f32x4 acc[4] = {z, z, z, z};

    if (ot < 8) {   // q,k : D[row=n][col=o]
        int nrow = nt * 64 + w * 16 + l15;
        const bf16x8* Arow = reinterpret_cast<const bf16x8*>(hTb + (size_t)nrow * C_);
        #pragma unroll
        for (int kk = 0; kk < 8; kk++) {
            bf16x8 a = Arow[kk * 4 + g];
            #pragma unroll
            for (int j = 0; j < 4; j++) {
                int orow = ot * 64 + j * 16 + l15;
                bf16x8 bfr = reinterpret_cast<const bf16x8*>(Wb + (size_t)orow * C_)[kk * 4 + g];
                acc[j] = mfma16(a, bfr, acc[j]);
            }
        }
        #pragma unroll
        for (int j = 0; j < 4; j++) {
            int o = ot * 64 + j * 16 + l15;
            float bias = qkvb[o];
            bool isq = (o < 256);
            float scl = isq ? 0.0625f : 1.0f;
            uint16_t* dst = isq ? (qT + (size_t)b * N_ * C_ + o)
                                : (kT + (size_t)b * N_ * C_ + (o - 256));
            #pragma unroll
            for (int r = 0; r < 4; r++) {
                int n = nt * 64 + w * 16 + g * 4 + r;
                dst[(size_t)n * C_] = f2bf((acc[j][r] + bias) * scl);
            }
        }
    } else {        // v : D[row=o'][col=n]
        int orow = ot * 64 + w * 16 + l15;   // 512..767
        const bf16x8* Arow = reinterpret_cast<const bf16x8*>(Wb + (size_t)orow * C_);
        #pragma unroll
        for (int kk = 0; kk < 8; kk++) {
            bf16x8 a = Arow[kk * 4 + g];
            #pragma unroll
            for (int j = 0; j < 4; j++) {
                int nrow = nt * 64 + j * 16 + l15;
                bf16x8 bfr = reinterpret_cast<const bf16x8*>(hTb + (size_t)nrow * C_)[kk * 4 + g];
                acc[j] = mfma16(a, bfr, acc[j]);
            }
        }
        #pragma unroll
        for (int j = 0; j < 4; j++) {
            #pragma unroll
            for (int r = 0; r < 4; r++) {
                int o = ot * 64 + w * 16 + g * 4 + r;
                int n = nt * 64 + j * 16 + l15;
                vO[(size_t)b * C_ * N_ + (size_t)(o - 512) * N_ + n] = f2bf(acc[j][r] + qkvb[o]);
            }
        }
    }
}

// ---------------- Flash attention: 8 waves, 4-way key split ----------------
// 512 thr: rg = w&1 (rows nb..nb+32), quarter q = w>>1 (key tiles q*32+t).
// Per quarter single-buffered chunk-major LDS (conflict-free, r11-verified):
//   Kt[q]: [32 chunk16B][32 key][8 ch]   Vt[q]: [4 chunk16B][256 ch][8 key]
// Iter: compute(t) -> barrier -> stage(t+1) -> barrier (vmcnt drained).
// QK^T: 4 indep chains; static-max softmax; PV via plds (pitch 40).
// Epilogue: lsum -> lbuf; O summed over quarters by 3-phase LDS tree
// (Oset0/1 alias dead Kt/Vt); q0 normalizes + stores.
__global__ __launch_bounds__(512, 2) void attn_kernel(
        const uint16_t* __restrict__ qT, const uint16_t* __restrict__ kT,
        const uint16_t* __restrict__ vO, uint16_t* __restrict__ h2T) {
    int blk = blockIdx.x;
    int xx = blk & 7;
    int b  = xx >> 1;
    int qt = (blk >> 3) * 2 + (xx & 1);       // 0..63
    int lane = threadIdx.x & 63, w = threadIdx.x >> 6;   // w in 0..7
    int rg = w & 1, q = w >> 1;               // rowgroup, key-quarter
    int l31 = lane & 31, g5 = lane >> 5;
    const uint16_t* qTb = qT + (size_t)b * N_ * C_;
    const uint16_t* kTb = kT + (size_t)b * N_ * C_;
    const uint16_t* vb  = vO + (size_t)b * C_ * N_;
    int nb = qt * 64 + rg * 32;

    __shared__ __align__(16) char smem[151552];
    uint16_t* Ktp = reinterpret_cast<uint16_t*>(smem) + q * 8192;           // 16 KB/q
    uint16_t* Vtp = reinterpret_cast<uint16_t*>(smem + 65536) + q * 8192;   // 16 KB/q
    uint16_t* plw = reinterpret_cast<uint16_t*>(smem + 131072) + w * 1280;  // [32][40]

    // Q fragments: A[row=l31][k=s*16 + g5*8 + j]
    bf16x8 afr[16];
    {
        const uint16_t* qrow = qTb + (size_t)(nb + l31) * C_;
        #pragma unroll
        for (int s = 0; s < 16; s++)
            afr[s] = *reinterpret_cast<const bf16x8*>(qrow + s * 16 + g5 * 8);
    }

    f32x16 acc[8];
    #pragma unroll
    for (int i = 0; i < 8; i++) acc[i] = (f32x16){};
    float lsum[16];
    #pragma unroll
    for (int i = 0; i < 16; i++) lsum[i] = 0.f;

    // wave (rg,q) stages its half of quarter q's tile (linear dests)
    auto stage = [&](int mb) {
        #pragma unroll
        for (int i = 0; i < 8; i++) {         // K: 2 chunk-cols x 32 keys / instr
            int c2 = rg * 16 + i * 2;
            gload16(kTb + (size_t)(mb + l31) * C_ + (c2 + g5) * 8, Ktp + c2 * 256);
        }
        #pragma unroll
        for (int i = 0; i < 8; i++) {         // V: 1 chunk x 64 ch / instr
            int c   = i >> 1;
            int cb3 = rg * 128 + (i & 1) * 64;
            gload16(vb + (size_t)(cb3 + lane) * N_ + mb + c * 8, Vtp + c * 2048 + cb3 * 8);
        }
    };

    stage(q * 32 * KVB);
    __syncthreads();

    for (int mt = 0; mt < 32; mt++) {
        // ---- QK^T: 4 independent accumulator chains ----
        f32x16 sc0 = (f32x16){}, sc1 = (f32x16){}, sc2 = (f32x16){}, sc3 = (f32x16){};
        #pragma unroll
        for (int s4 = 0; s4 < 4; s4++) {
            bf16x8 k0 = *reinterpret_cast<const bf16x8*>(Ktp + ((s4 * 4 + 0) * 2 + g5) * 256 + l31 * 8);
            bf16x8 k1 = *reinterpret_cast<const bf16x8*>(Ktp + ((s4 * 4 + 1) * 2 + g5) * 256 + l31 * 8);
            bf16x8 k2 = *reinterpret_cast<const bf16x8*>(Ktp + ((s4 * 4 + 2) * 2 + g5) * 256 + l31 * 8);
            bf16x8 k3 = *reinterpret_cast<const bf16x8*>(Ktp + ((s4 * 4 + 3) * 2 + g5) * 256 + l31 * 8);
            sc0 = mfma32(afr[s4 * 4 + 0], k0, sc0);
            sc1 = mfma32(afr[s4 * 4 + 1], k1, sc1);
            sc2 = mfma32(afr[s4 * 4 + 2], k2, sc2);
            sc3 = mfma32(afr[s4 * 4 + 3], k3, sc3);
        }
        f32x16 sc = (sc0 + sc1) + (sc2 + sc3);

        // ---- static-max softmax ----
        #pragma unroll
        for (int reg = 0; reg < 16; reg++) {
            float p = __expf(sc[reg]);
            lsum[reg] += p;
            int row = (reg & 3) + 8 * (reg >> 2) + 4 * g5;
            plw[row * 40 + l31] = f2bf(p);
        }

        bf16x8 pf0 = *reinterpret_cast<const bf16x8*>(plw + l31 * 40 + g5 * 8);
        bf16x8 pf1 = *reinterpret_cast<const bf16x8*>(plw + l31 * 40 + 16 + g5 * 8);

        // ---- PV: 8 indep chains ----
        #pragma unroll
        for (int ct = 0; ct < 8; ct++) {
            int ch8 = (ct * 32 + l31) * 8;
            bf16x8 v0 = *reinterpret_cast<const bf16x8*>(Vtp + g5 * 2048 + ch8);
            bf16x8 v1 = *reinterpret_cast<const bf16x8*>(Vtp + (2 + g5) * 2048 + ch8);
            acc[ct] = mfma32(v0, pf0, acc[ct]);
            acc[ct] = mfma32(v1, pf1, acc[ct]);
        }

        __syncthreads();                       // all waves done reading buffers
        if (mt + 1 < 32) stage((q * 32 + mt + 1) * KVB);
        __syncthreads();                       // vmcnt drained: buffers ready
    }

    // ---- lsum reduce (32-lane groups) -> lbuf ----
    #pragma unroll
    for (int d = 1; d < 32; d <<= 1) {
        #pragma unroll
        for (int reg = 0; reg < 16; reg++) lsum[reg] += __shfl_xor(lsum[reg], d);
    }
    float* Oset0 = reinterpret_cast<float*>(smem);             // [2rg][32][260] f32
    float* Oset1 = reinterpret_cast<float*>(smem + 66560);
    float* lbuf  = reinterpret_cast<float*>(smem + 133120);    // [4q][2rg][32]
    if ((lane & 31) == 0) {
        #pragma unroll
        for (int reg = 0; reg < 16; reg++) {
            int row = (reg & 3) + 8 * (reg >> 2) + 4 * g5;
            lbuf[(q * 2 + rg) * 32 + row] = lsum[reg];
        }
    }
    // ---- 3-phase quarter-sum tree: (1,3) write; (0,2) add; 2 writes; 0 adds ----
    auto owrite = [&](float* Os) {
        #pragma unroll
        for (int ct = 0; ct < 8; ct++) {
            #pragma unroll
            for (int qd = 0; qd < 4; qd++) {
                f32x4 v = {acc[ct][qd * 4 + 0], acc[ct][qd * 4 + 1],
                           acc[ct][qd * 4 + 2], acc[ct][qd * 4 + 3]};
                *reinterpret_cast<f32x4*>(
                    &Os[(size_t)(rg * 32 + l31) * 260 + ct * 32 + qd * 8 + 4 * g5]) = v;
            }
        }
    };
    auto oadd = [&](const float* Os) {
        #pragma unroll
        for (int ct = 0; ct < 8; ct++) {
            #pragma unroll
            for (int qd = 0; qd < 4; qd++) {
                f32x4 v = *reinterpret_cast<const f32x4*>(
                    &Os[(size_t)(rg * 32 + l31) * 260 + ct * 32 + qd * 8 + 4 * g5]);
                acc[ct][qd * 4 + 0] += v[0]; acc[ct][qd * 4 + 1] += v[1];
                acc[ct][qd * 4 + 2] += v[2]; acc[ct][qd * 4 + 3] += v[3];
            }
        }
    };
    if (q == 1) owrite(Oset0);
    if (q == 3) owrite(Oset1);
    __syncthreads();
    if (q == 0) oadd(Oset0);
    if (q == 2) oadd(Oset1);
    __syncthreads();
    if (q == 2) owrite(Oset0);
    __syncthreads();
    if (q == 0) {
        oadd(Oset0);
        float lt = lbuf[rg * 32 + l31] + lbuf[(2 + rg) * 32 + l31] +
                   lbuf[(4 + rg) * 32 + l31] + lbuf[(6 + rg) * 32 + l31];
        float inv = 1.0f / lt;
        uint16_t* rowp = h2T + ((size_t)b * N_ + nb + l31) * C_;
        #pragma unroll
        for (int ct = 0; ct < 8; ct++) {
            #pragma unroll
            for (int qd = 0; qd < 4; qd++) {
                uint32_t lo = f2bf(acc[ct][qd * 4 + 0] * inv) |
                              ((uint32_t)f2bf(acc[ct][qd * 4 + 1] * inv) << 16);
                uint32_t hi = f2bf(acc[ct][qd * 4 + 2] * inv) |
                              ((uint32_t)f2bf(acc[ct][qd * 4 + 3] * inv) << 16);
                uint2 val = {lo, hi};
                *reinterpret_cast<uint2*>(rowp + ct * 32 + qd * 8 + 4 * g5) = val;
            }
        }
    }
}

// ---------------- proj GEMM + bias + residual ----------------
__global__ __launch_bounds__(256) void proj_gemm(
        const uint16_t* __restrict__ Pwb, const float* __restrict__ pb,
        const uint16_t* __restrict__ h2T, const float* __restrict__ x,
        float* __restrict__ out) {
    int nt = blockIdx.x, ct = blockIdx.y, b = blockIdx.z;
    int lane = threadIdx.x & 63, w = threadIdx.x >> 6;
    int l15 = lane & 15, g = lane >> 4;
    const uint16_t* h2Tb = h2T + (size_t)b * N_ * C_;
    f32x4 z = {0.f, 0.f, 0.f, 0.f};
    f32x4 acc[4] = {z, z, z, z};
    int crow = ct * 64 + w * 16 + l15;
    const bf16x8* Arow = reinterpret_cast<const bf16x8*>(Pwb + (size_t)crow * C_);
    #pragma unroll
    for (int kk = 0; kk < 8; kk++) {
        bf16x8 a = Arow[kk * 4 + g];
        #pragma unroll
        for (int j = 0; j < 4; j++) {
            bf16x8 bfr = reinterpret_cast<const bf16x8*>(
                h2Tb + (size_t)(nt * 64 + j * 16 + l15) * C_)[kk * 4 + g];
            acc[j] = mfma16(a, bfr, acc[j]);
        }
    }
    #pragma unroll
    for (int j = 0; j < 4; j++) {
        #pragma unroll
        for (int r = 0; r < 4; r++) {
            int c = ct * 64 + w * 16 + g * 4 + r;
            int n = nt * 64 + j * 16 + l15;
            size_t idx = ((size_t)b * C_ + c) * N_ + n;
            out[idx] = x[idx] + acc[j][r] + pb[c];
        }
    }
}

extern "C" void kernel_launch(void* const* d_in, const int* in_sizes, int n_in,
                              void* d_out, int out_size, void* d_ws, size_t ws_size,
                              hipStream_t stream) {
    const float* x      = (const float*)d_in[0];
    const float* gn_w   = (const float*)d_in[1];
    const float* gn_b   = (const float*)d_in[2];
    const float* qkv_w  = (const float*)d_in[3];
    const float* qkv_b  = (const float*)d_in[4];
    const float* proj_w = (const float*)d_in[5];
    const float* proj_b = (const float*)d_in[6];
    float* out = (float*)d_out;

    char* ws = (char*)d_ws;
    float*    stats  = (float*)(ws);                          // 256 B
    float2*   part   = (float2*)(ws + 8192);                  // 8 KB
    uint16_t* qkvwb  = (uint16_t*)(ws + 65536);               // 384 KB
    uint16_t* projwb = (uint16_t*)(ws + 65536 + 768 * 256 * 2);
    uint16_t* hT     = (uint16_t*)(ws + (size_t)(1)  * (1 << 20));  // 8 MB [B][N][C]
    uint16_t* qT     = (uint16_t*)(ws + (size_t)(9)  * (1 << 20));  // 8 MB [B][N][C]
    uint16_t* kT     = (uint16_t*)(ws + (size_t)(17) * (1 << 20));  // 8 MB [B][N][C]
    uint16_t* vO     = (uint16_t*)(ws + (size_t)(25) * (1 << 20));  // 8 MB [B][C][N]
    uint16_t* h2T    = (uint16_t*)(ws + (size_t)(33) * (1 << 20));  // 8 MB [B][N][C]

    cast_weights<<<dim3(1024), dim3(256), 0, stream>>>(qkv_w, proj_w, qkvwb, projwb);
    gn_stats1<<<dim3(1024), dim3(256), 0, stream>>>(x, part);
    gn_stats2<<<dim3(1), dim3(1024), 0, stream>>>(part, stats);
    gn_apply<<<dim3(64, 4, 4), dim3(256), 0, stream>>>(x, gn_w, gn_b, stats, hT);
    qkv_gemm<<<dim3(64, 12, 4), dim3(256), 0, stream>>>(qkvwb, qkv_b, hT, qT, kT, vO);
    attn_kernel<<<dim3(256), dim3(512), 0, stream>>>(qT, kT, vO, h2T);
    proj_gemm<<<dim3(64, 4, 4), dim3(256), 0, stream>>>(projwb, proj_b, h2T, x, out);
}

// Round 14
// 351.024 us; speedup vs baseline: 1.3293x; 1.3293x over previous
//
#include <hip/hip_runtime.h>
#include <stdint.h>

// AttentionBlock: GN -> QKV -> softmax(QK^T/sqrt(C)) V -> proj + residual
// B=4, C=256, H=W=64, N=4096, groups=8 (32 ch/group)
// All matmuls bf16 MFMA (fp32 accumulate). fp32 threshold 0.1 absmax.
//
// Round 14 = round 13 minus the VGPR blowout: QK back to a SINGLE MFMA
// accumulator chain (acc128+afr64+sc16+lsum16+misc ~= 240 <= 256 budget at
// 2 waves/SIMD; r13's 4-chain ILP spilled ~18 regs -> 308MB scratch traffic).
// 8 waves (512 thr): rg = w&1 (32 q-rows), quarter q = w>>1 sweeps 32 of 128
// key tiles; single-buffered chunk-major K/V LDS (148 KB, conflict-free);
// compute -> barrier -> stage -> barrier; static-max softmax; 4-way O/l sum.

#define B_ 4
#define C_ 256
#define N_ 4096
#define KVB 32

using bf16x8 = __attribute__((ext_vector_type(8))) __bf16;
using f32x4  = __attribute__((ext_vector_type(4))) float;
using f32x16 = __attribute__((ext_vector_type(16))) float;

__device__ __forceinline__ uint16_t f2bf(float f) {
    uint32_t u = __float_as_uint(f);
    u = (u + 0x7fffu + ((u >> 16) & 1u)) >> 16;   // RNE
    return (uint16_t)u;
}

__device__ __forceinline__ f32x4 mfma16(bf16x8 a, bf16x8 b, f32x4 c) {
    return __builtin_amdgcn_mfma_f32_16x16x32_bf16(a, b, c, 0, 0, 0);
}

__device__ __forceinline__ f32x16 mfma32(bf16x8 a, bf16x8 b, f32x16 c) {
    return __builtin_amdgcn_mfma_f32_32x32x16_bf16(a, b, c, 0, 0, 0);
}

__device__ __forceinline__ void gload16(const void* g, void* l) {
    __builtin_amdgcn_global_load_lds(
        (const __attribute__((address_space(1))) uint32_t*)g,
        (__attribute__((address_space(3))) uint32_t*)l, 16, 0, 0);
}

// ---------------- cast weights to bf16 ----------------
__global__ __launch_bounds__(256) void cast_weights(
        const float* __restrict__ qkvw, const float* __restrict__ projw,
        uint16_t* __restrict__ qkvwb, uint16_t* __restrict__ projwb) {
    int i = blockIdx.x * 256 + threadIdx.x;
    if (i < 768 * 256) qkvwb[i] = f2bf(qkvw[i]);
    int j = i - 768 * 256;
    if (j >= 0 && j < 256 * 256) projwb[j] = f2bf(projw[j]);
}

// ---------------- GroupNorm stats, two-stage ----------------
__global__ __launch_bounds__(256) void gn_stats1(const float* __restrict__ x,
                                                 float2* __restrict__ part) {
    int i = blockIdx.x;
    const float4* p = reinterpret_cast<const float4*>(x + (size_t)i * 4096);
    float s = 0.f, ss = 0.f;
    #pragma unroll
    for (int j = 0; j < 4; j++) {
        float4 v = p[threadIdx.x + j * 256];
        s  += v.x + v.y + v.z + v.w;
        ss += v.x*v.x + v.y*v.y + v.z*v.z + v.w*v.w;
    }
    #pragma unroll
    for (int d = 32; d > 0; d >>= 1) { s += __shfl_down(s, d); ss += __shfl_down(ss, d); }
    __shared__ float rs[4], rss[4];
    int wid = threadIdx.x >> 6;
    if ((threadIdx.x & 63) == 0) { rs[wid] = s; rss[wid] = ss; }
    __syncthreads();
    if (threadIdx.x == 0) {
        float2 o;
        o.x = rs[0] + rs[1] + rs[2] + rs[3];
        o.y = rss[0] + rss[1] + rss[2] + rss[3];
        part[i] = o;
    }
}
__global__ __launch_bounds__(1024) void gn_stats2(const float2* __restrict__ part,
                                                  float* __restrict__ stats) {
    int t = threadIdx.x;
    int g = t >> 5, j = t & 31;
    float2 v = part[g * 32 + j];
    float s = v.x, ss = v.y;
    #pragma unroll
    for (int d = 16; d > 0; d >>= 1) { s += __shfl_xor(s, d); ss += __shfl_xor(ss, d); }
    if (j == 0) {
        float mean = s / 131072.f;
        float var  = ss / 131072.f - mean * mean;
        stats[g * 2]     = mean;
        stats[g * 2 + 1] = rsqrtf(var + 1e-5f);
    }
}

// ---------------- GN apply + transpose: hT[b][n][c] bf16 ----------------
__global__ __launch_bounds__(256) void gn_apply(
        const float* __restrict__ x, const float* __restrict__ gnw,
        const float* __restrict__ gnb, const float* __restrict__ stats,
        uint16_t* __restrict__ hT) {
    int nb = blockIdx.x * 64, cb = blockIdx.y * 64, b = blockIdx.z;
    __shared__ uint16_t lds[64][64];          // [n][c]
    int t = threadIdx.x;
    int c_l = t >> 4;
    int n4  = (t & 15) * 4;
    #pragma unroll
    for (int i = 0; i < 4; i++) {
        int c = cb + c_l + 16 * i;
        int sg = b * 8 + (c >> 5);
        float mean = stats[sg * 2], rstd = stats[sg * 2 + 1];
        float sc = gnw[c] * rstd;
        float sh = gnb[c] - mean * sc;
        float4 v = *reinterpret_cast<const float4*>(x + ((size_t)b * C_ + c) * N_ + nb + n4);
        lds[n4 + 0][c_l + 16 * i] = f2bf(fmaf(v.x, sc, sh));
        lds[n4 + 1][c_l + 16 * i] = f2bf(fmaf(v.y, sc, sh));
        lds[n4 + 2][c_l + 16 * i] = f2bf(fmaf(v.z, sc, sh));
        lds[n4 + 3][c_l + 16 * i] = f2bf(fmaf(v.w, sc, sh));
    }
    __syncthreads();
    int n_l = t >> 2, c16 = (t & 3) * 16;
    uint4* dst = reinterpret_cast<uint4*>(hT + ((size_t)b * N_ + nb + n_l) * C_ + cb + c16);
    const uint4* sp = reinterpret_cast<const uint4*>(&lds[n_l][c16]);
    dst[0] = sp[0]; dst[1] = sp[1];
}

// ---------------- QKV GEMM ----------------
// q,k transposed [n][o]; q pre-scaled by 1/16 (softmax scale). v kept [o'][n].
__global__ __launch_bounds__(256) void qkv_gemm(
        const uint16_t* __restrict__ Wb, const float* __restrict__ qkvb,
        const uint16_t* __restrict__ hT, uint16_t* __restrict__ qT,
        uint16_t* __restrict__ kT, uint16_t* __restrict__ vO) {
    int nt = blockIdx.x, ot = blockIdx.y, b = blockIdx.z;
    int lane = threadIdx.x & 63, w = threadIdx.x >> 6;
    int l15 = lane & 15, g = lane >> 4;
    const uint16_t* hTb = hT + (size_t)b * N_ * C_;
    f32x4 z = {0.f, 0.f, 0.f, 0.f};
    f32x4 acc[4] = {z, z, z, z};

    if (ot < 8) {   // q,k : D[row=n][col=o]
        int nrow = nt * 64 + w * 16 + l15;
        const bf16x8* Arow = reinterpret_cast<const bf16x8*>(hTb + (size_t)nrow * C_);
        #pragma unroll
        for (int kk = 0; kk < 8; kk++) {
            bf16x8 a = Arow[kk * 4 + g];
            #pragma unroll
            for (int j = 0; j < 4; j++) {
                int orow = ot * 64 + j * 16 + l15;
                bf16x8 bfr = reinterpret_cast<const bf16x8*>(Wb + (size_t)orow * C_)[kk * 4 + g];
                acc[j] = mfma16(a, bfr, acc[j]);
            }
        }
        #pragma unroll
        for (int j = 0; j < 4; j++) {
            int o = ot * 64 + j * 16 + l15;
            float bias = qkvb[o];
            bool isq = (o < 256);
            float scl = isq ? 0.0625f : 1.0f;
            uint16_t* dst = isq ? (qT + (size_t)b * N_ * C_ + o)
                                : (kT + (size_t)b * N_ * C_ + (o - 256));
            #pragma unroll
            for (int r = 0; r < 4; r++) {
                int n = nt * 64 + w * 16 + g * 4 + r;
                dst[(size_t)n * C_] = f2bf((acc[j][r] + bias) * scl);
            }
        }
    } else {        // v : D[row=o'][col=n]
        int orow = ot * 64 + w * 16 + l15;   // 512..767
        const bf16x8* Arow = reinterpret_cast<const bf16x8*>(Wb + (size_t)orow * C_);
        #pragma unroll
        for (int kk = 0; kk < 8; kk++) {
            bf16x8 a = Arow[kk * 4 + g];
            #pragma unroll
            for (int j = 0; j < 4; j++) {
                int nrow = nt * 64 + j * 16 + l15;
                bf16x8 bfr = reinterpret_cast<const bf16x8*>(hTb + (size_t)nrow * C_)[kk * 4 + g];
                acc[j] = mfma16(a, bfr, acc[j]);
            }
        }
        #pragma unroll
        for (int j = 0; j < 4; j++) {
            #pragma unroll
            for (int r = 0; r < 4; r++) {
                int o = ot * 64 + w * 16 + g * 4 + r;
                int n = nt * 64 + j * 16 + l15;
                vO[(size_t)b * C_ * N_ + (size_t)(o - 512) * N_ + n] = f2bf(acc[j][r] + qkvb[o]);
            }
        }
    }
}

// ---------------- Flash attention: 8 waves, 4-way key split ----------------
// 512 thr: rg = w&1 (rows nb..nb+32), quarter q = w>>1 (key tiles q*32+t).
// Per quarter single-buffered chunk-major LDS (conflict-free, r11-verified):
//   Kt[q]: [32 chunk16B][32 key][8 ch]   Vt[q]: [4 chunk16B][256 ch][8 key]
// Iter: compute(t) -> barrier -> stage(t+1) -> barrier (vmcnt drained).
// QK^T: SINGLE chain (fits 256-VGPR budget at 2 waves/SIMD; the co-resident
// wave hides the chain latency). Static-max softmax; PV via plds (pitch 40).
// Epilogue: lsum -> lbuf; O summed over quarters by 3-phase LDS tree.
__global__ __launch_bounds__(512, 2) void attn_kernel(
        const uint16_t* __restrict__ qT, const uint16_t* __restrict__ kT,
        const uint16_t* __restrict__ vO, uint16_t* __restrict__ h2T) {
    int blk = blockIdx.x;
    int xx = blk & 7;
    int b  = xx >> 1;
    int qt = (blk >> 3) * 2 + (xx & 1);       // 0..63
    int lane = threadIdx.x & 63, w = threadIdx.x >> 6;   // w in 0..7
    int rg = w & 1, q = w >> 1;               // rowgroup, key-quarter
    int l31 = lane & 31, g5 = lane >> 5;
    const uint16_t* qTb = qT + (size_t)b * N_ * C_;
    const uint16_t* kTb = kT + (size_t)b * N_ * C_;
    const uint16_t* vb  = vO + (size_t)b * C_ * N_;
    int nb = qt * 64 + rg * 32;

    __shared__ __align__(16) char smem[151552];
    uint16_t* Ktp = reinterpret_cast<uint16_t*>(smem) + q * 8192;           // 16 KB/q
    uint16_t* Vtp = reinterpret_cast<uint16_t*>(smem + 65536) + q * 8192;   // 16 KB/q
    uint16_t* plw = reinterpret_cast<uint16_t*>(smem + 131072) + w * 1280;  // [32][40]

    // Q fragments: A[row=l31][k=s*16 + g5*8 + j]
    bf16x8 afr[16];
    {
        const uint16_t* qrow = qTb + (size_t)(nb + l31) * C_;
        #pragma unroll
        for (int s = 0; s < 16; s++)
            afr[s] = *reinterpret_cast<const bf16x8*>(qrow + s * 16 + g5 * 8);
    }

    f32x16 acc[8];
    #pragma unroll
    for (int i = 0; i < 8; i++) acc[i] = (f32x16){};
    float lsum[16];
    #pragma unroll
    for (int i = 0; i < 16; i++) lsum[i] = 0.f;

    // wave (rg,q) stages its half of quarter q's tile (linear dests)
    auto stage = [&](int mb) {
        #pragma unroll
        for (int i = 0; i < 8; i++) {         // K: 2 chunk-cols x 32 keys / instr
            int c2 = rg * 16 + i * 2;
            gload16(kTb + (size_t)(mb + l31) * C_ + (c2 + g5) * 8, Ktp + c2 * 256);
        }
        #pragma unroll
        for (int i = 0; i < 8; i++) {         // V: 1 chunk x 64 ch / instr
            int c   = i >> 1;
            int cb3 = rg * 128 + (i & 1) * 64;
            gload16(vb + (size_t)(cb3 + lane) * N_ + mb + c * 8, Vtp + c * 2048 + cb3 * 8);
        }
    };

    stage(q * 32 * KVB);
    __syncthreads();

    for (int mt = 0; mt < 32; mt++) {
        // ---- QK^T: single accumulator chain (register-budget-safe) ----
        f32x16 sc = (f32x16){};
        #pragma unroll
        for (int s = 0; s < 16; s++) {
            bf16x8 kfr = *reinterpret_cast<const bf16x8*>(Ktp + (s * 2 + g5) * 256 + l31 * 8);
            sc = mfma32(afr[s], kfr, sc);
        }

        // ---- static-max softmax ----
        #pragma unroll
        for (int reg = 0; reg < 16; reg++) {
            float p = __expf(sc[reg]);
            lsum[reg] += p;
            int row = (reg & 3) + 8 * (reg >> 2) + 4 * g5;
            plw[row * 40 + l31] = f2bf(p);
        }

        bf16x8 pf0 = *reinterpret_cast<const bf16x8*>(plw + l31 * 40 + g5 * 8);
        bf16x8 pf1 = *reinterpret_cast<const bf16x8*>(plw + l31 * 40 + 16 + g5 * 8);

        // ---- PV: 8 indep chains ----
        #pragma unroll
        for (int ct = 0; ct < 8; ct++) {
            int ch8 = (ct * 32 + l31) * 8;
            bf16x8 v0 = *reinterpret_cast<const bf16x8*>(Vtp + g5 * 2048 + ch8);
            bf16x8 v1 = *reinterpret_cast<const bf16x8*>(Vtp + (2 + g5) * 2048 + ch8);
            acc[ct] = mfma32(v0, pf0, acc[ct]);
            acc[ct] = mfma32(v1, pf1, acc[ct]);
        }

        __syncthreads();                       // all waves done reading buffers
        if (mt + 1 < 32) stage((q * 32 + mt + 1) * KVB);
        __syncthreads();                       // vmcnt drained: buffers ready
    }

    // ---- lsum reduce (32-lane groups) -> lbuf ----
    #pragma unroll
    for (int d = 1; d < 32; d <<= 1) {
        #pragma unroll
        for (int reg = 0; reg < 16; reg++) lsum[reg] += __shfl_xor(lsum[reg], d);
    }
    float* Oset0 = reinterpret_cast<float*>(smem);             // [2rg][32][260] f32
    float* Oset1 = reinterpret_cast<float*>(smem + 66560);
    float* lbuf  = reinterpret_cast<float*>(smem + 133120);    // [4q][2rg][32]
    if ((lane & 31) == 0) {
        #pragma unroll
        for (int reg = 0; reg < 16; reg++) {
            int row = (reg & 3) + 8 * (reg >> 2) + 4 * g5;
            lbuf[(q * 2 + rg) * 32 + row] = lsum[reg];
        }
    }
    // ---- 3-phase quarter-sum tree: (1,3) write; (0,2) add; 2 writes; 0 adds ----
    auto owrite = [&](float* Os) {
        #pragma unroll
        for (int ct = 0; ct < 8; ct++) {
            #pragma unroll
            for (int qd = 0; qd < 4; qd++) {
                f32x4 v = {acc[ct][qd * 4 + 0], acc[ct][qd * 4 + 1],
                           acc[ct][qd * 4 + 2], acc[ct][qd * 4 + 3]};
                *reinterpret_cast<f32x4*>(
                    &Os[(size_t)(rg * 32 + l31) * 260 + ct * 32 + qd * 8 + 4 * g5]) = v;
            }
        }
    };
    auto oadd = [&](const float* Os) {
        #pragma unroll
        for (int ct = 0; ct < 8; ct++) {
            #pragma unroll
            for (int qd = 0; qd < 4; qd++) {
                f32x4 v = *reinterpret_cast<const f32x4*>(
                    &Os[(size_t)(rg * 32 + l31) * 260 + ct * 32 + qd * 8 + 4 * g5]);
                acc[ct][qd * 4 + 0] += v[0]; acc[ct][qd * 4 + 1] += v[1];
                acc[ct][qd * 4 + 2] += v[2]; acc[ct][qd * 4 + 3] += v[3];
            }
        }
    };
    if (q == 1) owrite(Oset0);
    if (q == 3) owrite(Oset1);
    __syncthreads();
    if (q == 0) oadd(Oset0);
    if (q == 2) oadd(Oset1);
    __syncthreads();
    if (q == 2) owrite(Oset0);
    __syncthreads();
    if (q == 0) {
        oadd(Oset0);
        float lt = lbuf[rg * 32 + l31] + lbuf[(2 + rg) * 32 + l31] +
                   lbuf[(4 + rg) * 32 + l31] + lbuf[(6 + rg) * 32 + l31];
        float inv = 1.0f / lt;
        uint16_t* rowp = h2T + ((size_t)b * N_ + nb + l31) * C_;
        #pragma unroll
        for (int ct = 0; ct < 8; ct++) {
            #pragma unroll
            for (int qd = 0; qd < 4; qd++) {
                uint32_t lo = f2bf(acc[ct][qd * 4 + 0] * inv) |
                              ((uint32_t)f2bf(acc[ct][qd * 4 + 1] * inv) << 16);
                uint32_t hi = f2bf(acc[ct][qd * 4 + 2] * inv) |
                              ((uint32_t)f2bf(acc[ct][qd * 4 + 3] * inv) << 16);
                uint2 val = {lo, hi};
                *reinterpret_cast<uint2*>(rowp + ct * 32 + qd * 8 + 4 * g5) = val;
            }
        }
    }
}

// ---------------- proj GEMM + bias + residual ----------------
__global__ __launch_bounds__(256) void proj_gemm(
        const uint16_t* __restrict__ Pwb, const float* __restrict__ pb,
        const uint16_t* __restrict__ h2T, const float* __restrict__ x,
        float* __restrict__ out) {
    int nt = blockIdx.x, ct = blockIdx.y, b = blockIdx.z;
    int lane = threadIdx.x & 63, w = threadIdx.x >> 6;
    int l15 = lane & 15, g = lane >> 4;
    const uint16_t* h2Tb = h2T + (size_t)b * N_ * C_;
    f32x4 z = {0.f, 0.f, 0.f, 0.f};
    f32x4 acc[4] = {z, z, z, z};
    int crow = ct * 64 + w * 16 + l15;
    const bf16x8* Arow = reinterpret_cast<const bf16x8*>(Pwb + (size_t)crow * C_);
    #pragma unroll
    for (int kk = 0; kk < 8; kk++) {
        bf16x8 a = Arow[kk * 4 + g];
        #pragma unroll
        for (int j = 0; j < 4; j++) {
            bf16x8 bfr = reinterpret_cast<const bf16x8*>(
                h2Tb + (size_t)(nt * 64 + j * 16 + l15) * C_)[kk * 4 + g];
            acc[j] = mfma16(a, bfr, acc[j]);
        }
    }
    #pragma unroll
    for (int j = 0; j < 4; j++) {
        #pragma unroll
        for (int r = 0; r < 4; r++) {
            int c = ct * 64 + w * 16 + g * 4 + r;
            int n = nt * 64 + j * 16 + l15;
            size_t idx = ((size_t)b * C_ + c) * N_ + n;
            out[idx] = x[idx] + acc[j][r] + pb[c];
        }
    }
}

extern "C" void kernel_launch(void* const* d_in, const int* in_sizes, int n_in,
                              void* d_out, int out_size, void* d_ws, size_t ws_size,
                              hipStream_t stream) {
    const float* x      = (const float*)d_in[0];
    const float* gn_w   = (const float*)d_in[1];
    const float* gn_b   = (const float*)d_in[2];
    const float* qkv_w  = (const float*)d_in[3];
    const float* qkv_b  = (const float*)d_in[4];
    const float* proj_w = (const float*)d_in[5];
    const float* proj_b = (const float*)d_in[6];
    float* out = (float*)d_out;

    char* ws = (char*)d_ws;
    float*    stats  = (float*)(ws);                          // 256 B
    float2*   part   = (float2*)(ws + 8192);                  // 8 KB
    uint16_t* qkvwb  = (uint16_t*)(ws + 65536);               // 384 KB
    uint16_t* projwb = (uint16_t*)(ws + 65536 + 768 * 256 * 2);
    uint16_t* hT     = (uint16_t*)(ws + (size_t)(1)  * (1 << 20));  // 8 MB [B][N][C]
    uint16_t* qT     = (uint16_t*)(ws + (size_t)(9)  * (1 << 20));  // 8 MB [B][N][C]
    uint16_t* kT     = (uint16_t*)(ws + (size_t)(17) * (1 << 20));  // 8 MB [B][N][C]
    uint16_t* vO     = (uint16_t*)(ws + (size_t)(25) * (1 << 20));  // 8 MB [B][C][N]
    uint16_t* h2T    = (uint16_t*)(ws + (size_t)(33) * (1 << 20));  // 8 MB [B][N][C]

    cast_weights<<<dim3(1024), dim3(256), 0, stream>>>(qkv_w, proj_w, qkvwb, projwb);
    gn_stats1<<<dim3(1024), dim3(256), 0, stream>>>(x, part);
    gn_stats2<<<dim3(1), dim3(1024), 0, stream>>>(part, stats);
    gn_apply<<<dim3(64, 4, 4), dim3(256), 0, stream>>>(x, gn_w, gn_b, stats, hT);
    qkv_gemm<<<dim3(64, 12, 4), dim3(256), 0, stream>>>(qkvwb, qkv_b, hT, qT, kT, vO);
    attn_kernel<<<dim3(256), dim3(512), 0, stream>>>(qT, kT, vO, h2T);
    proj_gemm<<<dim3(64, 4, 4), dim3(256), 0, stream>>>(projwb, proj_b, h2T, x, out);
}

// Round 15
// 336.800 us; speedup vs baseline: 1.3855x; 1.0422x over previous
//
#include <hip/hip_runtime.h>
#include <stdint.h>

// AttentionBlock: GN -> QKV -> softmax(QK^T/sqrt(C)) V -> proj + residual
// B=4, C=256, H=W=64, N=4096, groups=8 (32 ch/group)
// All matmuls bf16 MFMA (fp32 accumulate). fp32 threshold 0.1 absmax.
//
// Round 15 = round 14 with the REAL register fix + split staging:
//  * __launch_bounds__(512,2) was interpreted as 2 blocks/CU -> 128-VGPR cap
//    -> spills (r13: 308MB, r14: 15MB scratch traffic). Replaced with
//    amdgpu_waves_per_eu(2): 256-VGPR budget, live set ~240 fits, no spill.
//  * staging split at dependency points: QK(t) -> bar -> issue K(t+1) ->
//    softmax+PV(t) -> bar (K drain covered by PV) -> issue V(t+1) -> bar.
//    Only the V-stage latency stays exposed (was K+V).

#define B_ 4
#define C_ 256
#define N_ 4096
#define KVB 32

using bf16x8 = __attribute__((ext_vector_type(8))) __bf16;
using f32x4  = __attribute__((ext_vector_type(4))) float;
using f32x16 = __attribute__((ext_vector_type(16))) float;

__device__ __forceinline__ uint16_t f2bf(float f) {
    uint32_t u = __float_as_uint(f);
    u = (u + 0x7fffu + ((u >> 16) & 1u)) >> 16;   // RNE
    return (uint16_t)u;
}

__device__ __forceinline__ f32x4 mfma16(bf16x8 a, bf16x8 b, f32x4 c) {
    return __builtin_amdgcn_mfma_f32_16x16x32_bf16(a, b, c, 0, 0, 0);
}

__device__ __forceinline__ f32x16 mfma32(bf16x8 a, bf16x8 b, f32x16 c) {
    return __builtin_amdgcn_mfma_f32_32x32x16_bf16(a, b, c, 0, 0, 0);
}

__device__ __forceinline__ void gload16(const void* g, void* l) {
    __builtin_amdgcn_global_load_lds(
        (const __attribute__((address_space(1))) uint32_t*)g,
        (__attribute__((address_space(3))) uint32_t*)l, 16, 0, 0);
}

// ---------------- cast weights to bf16 ----------------
__global__ __launch_bounds__(256) void cast_weights(
        const float* __restrict__ qkvw, const float* __restrict__ projw,
        uint16_t* __restrict__ qkvwb, uint16_t* __restrict__ projwb) {
    int i = blockIdx.x * 256 + threadIdx.x;
    if (i < 768 * 256) qkvwb[i] = f2bf(qkvw[i]);
    int j = i - 768 * 256;
    if (j >= 0 && j < 256 * 256) projwb[j] = f2bf(projw[j]);
}

// ---------------- GroupNorm stats, two-stage ----------------
__global__ __launch_bounds__(256) void gn_stats1(const float* __restrict__ x,
                                                 float2* __restrict__ part) {
    int i = blockIdx.x;
    const float4* p = reinterpret_cast<const float4*>(x + (size_t)i * 4096);
    float s = 0.f, ss = 0.f;
    #pragma unroll
    for (int j = 0; j < 4; j++) {
        float4 v = p[threadIdx.x + j * 256];
        s  += v.x + v.y + v.z + v.w;
        ss += v.x*v.x + v.y*v.y + v.z*v.z + v.w*v.w;
    }
    #pragma unroll
    for (int d = 32; d > 0; d >>= 1) { s += __shfl_down(s, d); ss += __shfl_down(ss, d); }
    __shared__ float rs[4], rss[4];
    int wid = threadIdx.x >> 6;
    if ((threadIdx.x & 63) == 0) { rs[wid] = s; rss[wid] = ss; }
    __syncthreads();
    if (threadIdx.x == 0) {
        float2 o;
        o.x = rs[0] + rs[1] + rs[2] + rs[3];
        o.y = rss[0] + rss[1] + rss[2] + rss[3];
        part[i] = o;
    }
}
__global__ __launch_bounds__(1024) void gn_stats2(const float2* __restrict__ part,
                                                  float* __restrict__ stats) {
    int t = threadIdx.x;
    int g = t >> 5, j = t & 31;
    float2 v = part[g * 32 + j];
    float s = v.x, ss = v.y;
    #pragma unroll
    for (int d = 16; d > 0; d >>= 1) { s += __shfl_xor(s, d); ss += __shfl_xor(ss, d); }
    if (j == 0) {
        float mean = s / 131072.f;
        float var  = ss / 131072.f - mean * mean;
        stats[g * 2]     = mean;
        stats[g * 2 + 1] = rsqrtf(var + 1e-5f);
    }
}

// ---------------- GN apply + transpose: hT[b][n][c] bf16 ----------------
__global__ __launch_bounds__(256) void gn_apply(
        const float* __restrict__ x, const float* __restrict__ gnw,
        const float* __restrict__ gnb, const float* __restrict__ stats,
        uint16_t* __restrict__ hT) {
    int nb = blockIdx.x * 64, cb = blockIdx.y * 64, b = blockIdx.z;
    __shared__ uint16_t lds[64][64];          // [n][c]
    int t = threadIdx.x;
    int c_l = t >> 4;
    int n4  = (t & 15) * 4;
    #pragma unroll
    for (int i = 0; i < 4; i++) {
        int c = cb + c_l + 16 * i;
        int sg = b * 8 + (c >> 5);
        float mean = stats[sg * 2], rstd = stats[sg * 2 + 1];
        float sc = gnw[c] * rstd;
        float sh = gnb[c] - mean * sc;
        float4 v = *reinterpret_cast<const float4*>(x + ((size_t)b * C_ + c) * N_ + nb + n4);
        lds[n4 + 0][c_l + 16 * i] = f2bf(fmaf(v.x, sc, sh));
        lds[n4 + 1][c_l + 16 * i] = f2bf(fmaf(v.y, sc, sh));
        lds[n4 + 2][c_l + 16 * i] = f2bf(fmaf(v.z, sc, sh));
        lds[n4 + 3][c_l + 16 * i] = f2bf(fmaf(v.w, sc, sh));
    }
    __syncthreads();
    int n_l = t >> 2, c16 = (t & 3) * 16;
    uint4* dst = reinterpret_cast<uint4*>(hT + ((size_t)b * N_ + nb + n_l) * C_ + cb + c16);
    const uint4* sp = reinterpret_cast<const uint4*>(&lds[n_l][c16]);
    dst[0] = sp[0]; dst[1] = sp[1];
}

// ---------------- QKV GEMM ----------------
// q,k transposed [n][o]; q pre-scaled by 1/16 (softmax scale). v kept [o'][n].
__global__ __launch_bounds__(256) void qkv_gemm(
        const uint16_t* __restrict__ Wb, const float* __restrict__ qkvb,
        const uint16_t* __restrict__ hT, uint16_t* __restrict__ qT,
        uint16_t* __restrict__ kT, uint16_t* __restrict__ vO) {
    int nt = blockIdx.x, ot = blockIdx.y, b = blockIdx.z;
    int lane = threadIdx.x & 63, w = threadIdx.x >> 6;
    int l15 = lane & 15, g = lane >> 4;
    const uint16_t* hTb = hT + (size_t)b * N_ * C_;
    f32x4 z = {0.f, 0.f, 0.f, 0.f};
    f32x4 acc[4] = {z, z, z, z};

    if (ot < 8) {   // q,k : D[row=n][col=o]
        int nrow = nt * 64 + w * 16 + l15;
        const bf16x8* Arow = reinterpret_cast<const bf16x8*>(hTb + (size_t)nrow * C_);
        #pragma unroll
        for (int kk = 0; kk < 8; kk++) {
            bf16x8 a = Arow[kk * 4 + g];
            #pragma unroll
            for (int j = 0; j < 4; j++) {
                int orow = ot * 64 + j * 16 + l15;
                bf16x8 bfr = reinterpret_cast<const bf16x8*>(Wb + (size_t)orow * C_)[kk * 4 + g];
                acc[j] = mfma16(a, bfr, acc[j]);
            }
        }
        #pragma unroll
        for (int j = 0; j < 4; j++) {
            int o = ot * 64 + j * 16 + l15;
            float bias = qkvb[o];
            bool isq = (o < 256);
            float scl = isq ? 0.0625f : 1.0f;
            uint16_t* dst = isq ? (qT + (size_t)b * N_ * C_ + o)
                                : (kT + (size_t)b * N_ * C_ + (o - 256));
            #pragma unroll
            for (int r = 0; r < 4; r++) {
                int n = nt * 64 + w * 16 + g * 4 + r;
                dst[(size_t)n * C_] = f2bf((acc[j][r] + bias) * scl);
            }
        }
    } else {        // v : D[row=o'][col=n]
        int orow = ot * 64 + w * 16 + l15;   // 512..767
        const bf16x8* Arow = reinterpret_cast<const bf16x8*>(Wb + (size_t)orow * C_);
        #pragma unroll
        for (int kk = 0; kk < 8; kk++) {
            bf16x8 a = Arow[kk * 4 + g];
            #pragma unroll
            for (int j = 0; j < 4; j++) {
                int nrow = nt * 64 + j * 16 + l15;
                bf16x8 bfr = reinterpret_cast<const bf16x8*>(hTb + (size_t)nrow * C_)[kk * 4 + g];
                acc[j] = mfma16(a, bfr, acc[j]);
            }
        }
        #pragma unroll
        for (int j = 0; j < 4; j++) {
            #pragma unroll
            for (int r = 0; r < 4; r++) {
                int o = ot * 64 + w * 16 + g * 4 + r;
                int n = nt * 64 + j * 16 + l15;
                vO[(size_t)b * C_ * N_ + (size_t)(o - 512) * N_ + n] = f2bf(acc[j][r] + qkvb[o]);
            }
        }
    }
}

// ---------------- Flash attention: 8 waves, 4-way key split ----------------
// 512 thr: rg = w&1 (rows nb..nb+32), quarter q = w>>1 (key tiles q*32+t).
// Per quarter single-buffered chunk-major LDS (conflict-free, r11-verified):
//   Kt[q]: [32 chunk16B][32 key][8 ch]   Vt[q]: [4 chunk16B][256 ch][8 key]
// Iter: QK(t) -> bar -> issue stageK(t+1) -> softmax+PV(t) -> bar (K drain
// covered by PV) -> issue stageV(t+1) -> bar (V drain exposed).
// amdgpu_waves_per_eu(2): 256-VGPR budget (live ~240, no spill), 2 waves/SIMD.
// Epilogue: lsum -> lbuf; O summed over quarters by 3-phase LDS tree.
__global__ __launch_bounds__(512) __attribute__((amdgpu_waves_per_eu(2)))
void attn_kernel(
        const uint16_t* __restrict__ qT, const uint16_t* __restrict__ kT,
        const uint16_t* __restrict__ vO, uint16_t* __restrict__ h2T) {
    int blk = blockIdx.x;
    int xx = blk & 7;
    int b  = xx >> 1;
    int qt = (blk >> 3) * 2 + (xx & 1);       // 0..63
    int lane = threadIdx.x & 63, w = threadIdx.x >> 6;   // w in 0..7
    int rg = w & 1, q = w >> 1;               // rowgroup, key-quarter
    int l31 = lane & 31, g5 = lane >> 5;
    const uint16_t* qTb = qT + (size_t)b * N_ * C_;
    const uint16_t* kTb = kT + (size_t)b * N_ * C_;
    const uint16_t* vb  = vO + (size_t)b * C_ * N_;
    int nb = qt * 64 + rg * 32;

    __shared__ __align__(16) char smem[151552];
    uint16_t* Ktp = reinterpret_cast<uint16_t*>(smem) + q * 8192;           // 16 KB/q
    uint16_t* Vtp = reinterpret_cast<uint16_t*>(smem + 65536) + q * 8192;   // 16 KB/q
    uint16_t* plw = reinterpret_cast<uint16_t*>(smem + 131072) + w * 1280;  // [32][40]

    // Q fragments: A[row=l31][k=s*16 + g5*8 + j]
    bf16x8 afr[16];
    {
        const uint16_t* qrow = qTb + (size_t)(nb + l31) * C_;
        #pragma unroll
        for (int s = 0; s < 16; s++)
            afr[s] = *reinterpret_cast<const bf16x8*>(qrow + s * 16 + g5 * 8);
    }

    f32x16 acc[8];
    #pragma unroll
    for (int i = 0; i < 8; i++) acc[i] = (f32x16){};
    float lsum[16];
    #pragma unroll
    for (int i = 0; i < 16; i++) lsum[i] = 0.f;

    // wave (rg,q) stages its half of quarter q's tiles (linear dests)
    auto stageK = [&](int mb) {
        #pragma unroll
        for (int i = 0; i < 8; i++) {         // K: 2 chunk-cols x 32 keys / instr
            int c2 = rg * 16 + i * 2;
            gload16(kTb + (size_t)(mb + l31) * C_ + (c2 + g5) * 8, Ktp + c2 * 256);
        }
    };
    auto stageV = [&](int mb) {
        #pragma unroll
        for (int i = 0; i < 8; i++) {         // V: 1 chunk x 64 ch / instr
            int c   = i >> 1;
            int cb3 = rg * 128 + (i & 1) * 64;
            gload16(vb + (size_t)(cb3 + lane) * N_ + mb + c * 8, Vtp + c * 2048 + cb3 * 8);
        }
    };

    stageK(q * 32 * KVB);
    stageV(q * 32 * KVB);
    __syncthreads();

    for (int mt = 0; mt < 32; mt++) {
        int nmb = (q * 32 + mt + 1) * KVB;

        // ---- QK^T: single accumulator chain (register-budget-safe) ----
        f32x16 sc = (f32x16){};
        #pragma unroll
        for (int s = 0; s < 16; s++) {
            bf16x8 kfr = *reinterpret_cast<const bf16x8*>(Ktp + (s * 2 + g5) * 256 + l31 * 8);
            sc = mfma32(afr[s], kfr, sc);
        }

        __syncthreads();                       // all waves done reading K(t)
        if (mt + 1 < 32) stageK(nmb);          // async; drains at next barrier,
                                               // covered by softmax+PV below
        // ---- static-max softmax ----
        #pragma unroll
        for (int reg = 0; reg < 16; reg++) {
            float p = __expf(sc[reg]);
            lsum[reg] += p;
            int row = (reg & 3) + 8 * (reg >> 2) + 4 * g5;
            plw[row * 40 + l31] = f2bf(p);
        }

        bf16x8 pf0 = *reinterpret_cast<const bf16x8*>(plw + l31 * 40 + g5 * 8);
        bf16x8 pf1 = *reinterpret_cast<const bf16x8*>(plw + l31 * 40 + 16 + g5 * 8);

        // ---- PV: 8 indep chains ----
        #pragma unroll
        for (int ct = 0; ct < 8; ct++) {
            int ch8 = (ct * 32 + l31) * 8;
            bf16x8 v0 = *reinterpret_cast<const bf16x8*>(Vtp + g5 * 2048 + ch8);
            bf16x8 v1 = *reinterpret_cast<const bf16x8*>(Vtp + (2 + g5) * 2048 + ch8);
            acc[ct] = mfma32(v0, pf0, acc[ct]);
            acc[ct] = mfma32(v1, pf1, acc[ct]);
        }

        __syncthreads();                       // all waves done reading V(t);
                                               // own K(t+1) loads drained here
        if (mt + 1 < 32) stageV(nmb);
        __syncthreads();                       // V(t+1) drained; tiles ready
    }

    // ---- lsum reduce (32-lane groups) -> lbuf ----
    #pragma unroll
    for (int d = 1; d < 32; d <<= 1) {
        #pragma unroll
        for (int reg = 0; reg < 16; reg++) lsum[reg] += __shfl_xor(lsum[reg], d);
    }
    float* Oset0 = reinterpret_cast<float*>(smem);             // [2rg][32][260] f32
    float* Oset1 = reinterpret_cast<float*>(smem + 66560);
    float* lbuf  = reinterpret_cast<float*>(smem + 133120);    // [4q][2rg][32]
    if ((lane & 31) == 0) {
        #pragma unroll
        for (int reg = 0; reg < 16; reg++) {
            int row = (reg & 3) + 8 * (reg >> 2) + 4 * g5;
            lbuf[(q * 2 + rg) * 32 + row] = lsum[reg];
        }
    }
    // ---- 3-phase quarter-sum tree: (1,3) write; (0,2) add; 2 writes; 0 adds ----
    auto owrite = [&](float* Os) {
        #pragma unroll
        for (int ct = 0; ct < 8; ct++) {
            #pragma unroll
            for (int qd = 0; qd < 4; qd++) {
                f32x4 v = {acc[ct][qd * 4 + 0], acc[ct][qd * 4 + 1],
                           acc[ct][qd * 4 + 2], acc[ct][qd * 4 + 3]};
                *reinterpret_cast<f32x4*>(
                    &Os[(size_t)(rg * 32 + l31) * 260 + ct * 32 + qd * 8 + 4 * g5]) = v;
            }
        }
    };
    auto oadd = [&](const float* Os) {
        #pragma unroll
        for (int ct = 0; ct < 8; ct++) {
            #pragma unroll
            for (int qd = 0; qd < 4; qd++) {
                f32x4 v = *reinterpret_cast<const f32x4*>(
                    &Os[(size_t)(rg * 32 + l31) * 260 + ct * 32 + qd * 8 + 4 * g5]);
                acc[ct][qd * 4 + 0] += v[0]; acc[ct][qd * 4 + 1] += v[1];
                acc[ct][qd * 4 + 2] += v[2]; acc[ct][qd * 4 + 3] += v[3];
            }
        }
    };
    if (q == 1) owrite(Oset0);
    if (q == 3) owrite(Oset1);
    __syncthreads();
    if (q == 0) oadd(Oset0);
    if (q == 2) oadd(Oset1);
    __syncthreads();
    if (q == 2) owrite(Oset0);
    __syncthreads();
    if (q == 0) {
        oadd(Oset0);
        float lt = lbuf[rg * 32 + l31] + lbuf[(2 + rg) * 32 + l31] +
                   lbuf[(4 + rg) * 32 + l31] + lbuf[(6 + rg) * 32 + l31];
        float inv = 1.0f / lt;
        uint16_t* rowp = h2T + ((size_t)b * N_ + nb + l31) * C_;
        #pragma unroll
        for (int ct = 0; ct < 8; ct++) {
            #pragma unroll
            for (int qd = 0; qd < 4; qd++) {
                uint32_t lo = f2bf(acc[ct][qd * 4 + 0] * inv) |
                              ((uint32_t)f2bf(acc[ct][qd * 4 + 1] * inv) << 16);
                uint32_t hi = f2bf(acc[ct][qd * 4 + 2] * inv) |
                              ((uint32_t)f2bf(acc[ct][qd * 4 + 3] * inv) << 16);
                uint2 val = {lo, hi};
                *reinterpret_cast<uint2*>(rowp + ct * 32 + qd * 8 + 4 * g5) = val;
            }
        }
    }
}

// ---------------- proj GEMM + bias + residual ----------------
__global__ __launch_bounds__(256) void proj_gemm(
        const uint16_t* __restrict__ Pwb, const float* __restrict__ pb,
        const uint16_t* __restrict__ h2T, const float* __restrict__ x,
        float* __restrict__ out) {
    int nt = blockIdx.x, ct = blockIdx.y, b = blockIdx.z;
    int lane = threadIdx.x & 63, w = threadIdx.x >> 6;
    int l15 = lane & 15, g = lane >> 4;
    const uint16_t* h2Tb = h2T + (size_t)b * N_ * C_;
    f32x4 z = {0.f, 0.f, 0.f, 0.f};
    f32x4 acc[4] = {z, z, z, z};
    int crow = ct * 64 + w * 16 + l15;
    const bf16x8* Arow = reinterpret_cast<const bf16x8*>(Pwb + (size_t)crow * C_);
    #pragma unroll
    for (int kk = 0; kk < 8; kk++) {
        bf16x8 a = Arow[kk * 4 + g];
        #pragma unroll
        for (int j = 0; j < 4; j++) {
            bf16x8 bfr = reinterpret_cast<const bf16x8*>(
                h2Tb + (size_t)(nt * 64 + j * 16 + l15) * C_)[kk * 4 + g];
            acc[j] = mfma16(a, bfr, acc[j]);
        }
    }
    #pragma unroll
    for (int j = 0; j < 4; j++) {
        #pragma unroll
        for (int r = 0; r < 4; r++) {
            int c = ct * 64 + w * 16 + g * 4 + r;
            int n = nt * 64 + j * 16 + l15;
            size_t idx = ((size_t)b * C_ + c) * N_ + n;
            out[idx] = x[idx] + acc[j][r] + pb[c];
        }
    }
}

extern "C" void kernel_launch(void* const* d_in, const int* in_sizes, int n_in,
                              void* d_out, int out_size, void* d_ws, size_t ws_size,
                              hipStream_t stream) {
    const float* x      = (const float*)d_in[0];
    const float* gn_w   = (const float*)d_in[1];
    const float* gn_b   = (const float*)d_in[2];
    const float* qkv_w  = (const float*)d_in[3];
    const float* qkv_b  = (const float*)d_in[4];
    const float* proj_w = (const float*)d_in[5];
    const float* proj_b = (const float*)d_in[6];
    float* out = (float*)d_out;

    char* ws = (char*)d_ws;
    float*    stats  = (float*)(ws);                          // 256 B
    float2*   part   = (float2*)(ws + 8192);                  // 8 KB
    uint16_t* qkvwb  = (uint16_t*)(ws + 65536);               // 384 KB
    uint16_t* projwb = (uint16_t*)(ws + 65536 + 768 * 256 * 2);
    uint16_t* hT     = (uint16_t*)(ws + (size_t)(1)  * (1 << 20));  // 8 MB [B][N][C]
    uint16_t* qT     = (uint16_t*)(ws + (size_t)(9)  * (1 << 20));  // 8 MB [B][N][C]
    uint16_t* kT     = (uint16_t*)(ws + (size_t)(17) * (1 << 20));  // 8 MB [B][N][C]
    uint16_t* vO     = (uint16_t*)(ws + (size_t)(25) * (1 << 20));  // 8 MB [B][C][N]
    uint16_t* h2T    = (uint16_t*)(ws + (size_t)(33) * (1 << 20));  // 8 MB [B][N][C]

    cast_weights<<<dim3(1024), dim3(256), 0, stream>>>(qkv_w, proj_w, qkvwb, projwb);
    gn_stats1<<<dim3(1024), dim3(256), 0, stream>>>(x, part);
    gn_stats2<<<dim3(1), dim3(1024), 0, stream>>>(part, stats);
    gn_apply<<<dim3(64, 4, 4), dim3(256), 0, stream>>>(x, gn_w, gn_b, stats, hT);
    qkv_gemm<<<dim3(64, 12, 4), dim3(256), 0, stream>>>(qkvwb, qkv_b, hT, qT, kT, vO);
    attn_kernel<<<dim3(256), dim3(512), 0, stream>>>(qT, kT, vO, h2T);
    proj_gemm<<<dim3(64, 4, 4), dim3(256), 0, stream>>>(projwb, proj_b, h2T, x, out);
}

// Round 16
// 336.556 us; speedup vs baseline: 1.3865x; 1.0007x over previous
//
#include <hip/hip_runtime.h>
#include <stdint.h>

// AttentionBlock: GN -> QKV -> softmax(QK^T/sqrt(C)) V -> proj + residual
// B=4, C=256, H=W=64, N=4096, groups=8 (32 ch/group)
// All matmuls bf16 MFMA (fp32 accumulate). fp32 threshold 0.1 absmax.
//
// Round 16 = round 15 with the launch-bounds semantics fixed: second arg is
// min BLOCKS/CU on this toolchain (evidence: r11/r12 (256,1) allocated
// 152/208 VGPRs no-spill; (512,2) capped at 128 -> spills in r13-r15).
// (512,1) = 1 block/CU = 8 waves = 2 waves/EU -> 256-VGPR budget; live set
// ~240 fits, spills gone. All else identical to r15: 8 waves, 4-way key
// split, single-buffered chunk-major K/V LDS (0 conflicts), split staging
// (K after QK-bar covered by PV, V after PV-bar), static-max softmax.

#define B_ 4
#define C_ 256
#define N_ 4096
#define KVB 32

using bf16x8 = __attribute__((ext_vector_type(8))) __bf16;
using f32x4  = __attribute__((ext_vector_type(4))) float;
using f32x16 = __attribute__((ext_vector_type(16))) float;

__device__ __forceinline__ uint16_t f2bf(float f) {
    uint32_t u = __float_as_uint(f);
    u = (u + 0x7fffu + ((u >> 16) & 1u)) >> 16;   // RNE
    return (uint16_t)u;
}

__device__ __forceinline__ f32x4 mfma16(bf16x8 a, bf16x8 b, f32x4 c) {
    return __builtin_amdgcn_mfma_f32_16x16x32_bf16(a, b, c, 0, 0, 0);
}

__device__ __forceinline__ f32x16 mfma32(bf16x8 a, bf16x8 b, f32x16 c) {
    return __builtin_amdgcn_mfma_f32_32x32x16_bf16(a, b, c, 0, 0, 0);
}

__device__ __forceinline__ void gload16(const void* g, void* l) {
    __builtin_amdgcn_global_load_lds(
        (const __attribute__((address_space(1))) uint32_t*)g,
        (__attribute__((address_space(3))) uint32_t*)l, 16, 0, 0);
}

// ---------------- cast weights to bf16 ----------------
__global__ __launch_bounds__(256) void cast_weights(
        const float* __restrict__ qkvw, const float* __restrict__ projw,
        uint16_t* __restrict__ qkvwb, uint16_t* __restrict__ projwb) {
    int i = blockIdx.x * 256 + threadIdx.x;
    if (i < 768 * 256) qkvwb[i] = f2bf(qkvw[i]);
    int j = i - 768 * 256;
    if (j >= 0 && j < 256 * 256) projwb[j] = f2bf(projw[j]);
}

// ---------------- GroupNorm stats, two-stage ----------------
__global__ __launch_bounds__(256) void gn_stats1(const float* __restrict__ x,
                                                 float2* __restrict__ part) {
    int i = blockIdx.x;
    const float4* p = reinterpret_cast<const float4*>(x + (size_t)i * 4096);
    float s = 0.f, ss = 0.f;
    #pragma unroll
    for (int j = 0; j < 4; j++) {
        float4 v = p[threadIdx.x + j * 256];
        s  += v.x + v.y + v.z + v.w;
        ss += v.x*v.x + v.y*v.y + v.z*v.z + v.w*v.w;
    }
    #pragma unroll
    for (int d = 32; d > 0; d >>= 1) { s += __shfl_down(s, d); ss += __shfl_down(ss, d); }
    __shared__ float rs[4], rss[4];
    int wid = threadIdx.x >> 6;
    if ((threadIdx.x & 63) == 0) { rs[wid] = s; rss[wid] = ss; }
    __syncthreads();
    if (threadIdx.x == 0) {
        float2 o;
        o.x = rs[0] + rs[1] + rs[2] + rs[3];
        o.y = rss[0] + rss[1] + rss[2] + rss[3];
        part[i] = o;
    }
}
__global__ __launch_bounds__(1024) void gn_stats2(const float2* __restrict__ part,
                                                  float* __restrict__ stats) {
    int t = threadIdx.x;
    int g = t >> 5, j = t & 31;
    float2 v = part[g * 32 + j];
    float s = v.x, ss = v.y;
    #pragma unroll
    for (int d = 16; d > 0; d >>= 1) { s += __shfl_xor(s, d); ss += __shfl_xor(ss, d); }
    if (j == 0) {
        float mean = s / 131072.f;
        float var  = ss / 131072.f - mean * mean;
        stats[g * 2]     = mean;
        stats[g * 2 + 1] = rsqrtf(var + 1e-5f);
    }
}

// ---------------- GN apply + transpose: hT[b][n][c] bf16 ----------------
__global__ __launch_bounds__(256) void gn_apply(
        const float* __restrict__ x, const float* __restrict__ gnw,
        const float* __restrict__ gnb, const float* __restrict__ stats,
        uint16_t* __restrict__ hT) {
    int nb = blockIdx.x * 64, cb = blockIdx.y * 64, b = blockIdx.z;
    __shared__ uint16_t lds[64][64];          // [n][c]
    int t = threadIdx.x;
    int c_l = t >> 4;
    int n4  = (t & 15) * 4;
    #pragma unroll
    for (int i = 0; i < 4; i++) {
        int c = cb + c_l + 16 * i;
        int sg = b * 8 + (c >> 5);
        float mean = stats[sg * 2], rstd = stats[sg * 2 + 1];
        float sc = gnw[c] * rstd;
        float sh = gnb[c] - mean * sc;
        float4 v = *reinterpret_cast<const float4*>(x + ((size_t)b * C_ + c) * N_ + nb + n4);
        lds[n4 + 0][c_l + 16 * i] = f2bf(fmaf(v.x, sc, sh));
        lds[n4 + 1][c_l + 16 * i] = f2bf(fmaf(v.y, sc, sh));
        lds[n4 + 2][c_l + 16 * i] = f2bf(fmaf(v.z, sc, sh));
        lds[n4 + 3][c_l + 16 * i] = f2bf(fmaf(v.w, sc, sh));
    }
    __syncthreads();
    int n_l = t >> 2, c16 = (t & 3) * 16;
    uint4* dst = reinterpret_cast<uint4*>(hT + ((size_t)b * N_ + nb + n_l) * C_ + cb + c16);
    const uint4* sp = reinterpret_cast<const uint4*>(&lds[n_l][c16]);
    dst[0] = sp[0]; dst[1] = sp[1];
}

// ---------------- QKV GEMM ----------------
// q,k transposed [n][o]; q pre-scaled by 1/16 (softmax scale). v kept [o'][n].
__global__ __launch_bounds__(256) void qkv_gemm(
        const uint16_t* __restrict__ Wb, const float* __restrict__ qkvb,
        const uint16_t* __restrict__ hT, uint16_t* __restrict__ qT,
        uint16_t* __restrict__ kT, uint16_t* __restrict__ vO) {
    int nt = blockIdx.x, ot = blockIdx.y, b = blockIdx.z;
    int lane = threadIdx.x & 63, w = threadIdx.x >> 6;
    int l15 = lane & 15, g = lane >> 4;
    const uint16_t* hTb = hT + (size_t)b * N_ * C_;
    f32x4 z = {0.f, 0.f, 0.f, 0.f};
    f32x4 acc[4] = {z, z, z, z};

    if (ot < 8) {   // q,k : D[row=n][col=o]
        int nrow = nt * 64 + w * 16 + l15;
        const bf16x8* Arow = reinterpret_cast<const bf16x8*>(hTb + (size_t)nrow * C_);
        #pragma unroll
        for (int kk = 0; kk < 8; kk++) {
            bf16x8 a = Arow[kk * 4 + g];
            #pragma unroll
            for (int j = 0; j < 4; j++) {
                int orow = ot * 64 + j * 16 + l15;
                bf16x8 bfr = reinterpret_cast<const bf16x8*>(Wb + (size_t)orow * C_)[kk * 4 + g];
                acc[j] = mfma16(a, bfr, acc[j]);
            }
        }
        #pragma unroll
        for (int j = 0; j < 4; j++) {
            int o = ot * 64 + j * 16 + l15;
            float bias = qkvb[o];
            bool isq = (o < 256);
            float scl = isq ? 0.0625f : 1.0f;
            uint16_t* dst = isq ? (qT + (size_t)b * N_ * C_ + o)
                                : (kT + (size_t)b * N_ * C_ + (o - 256));
            #pragma unroll
            for (int r = 0; r < 4; r++) {
                int n = nt * 64 + w * 16 + g * 4 + r;
                dst[(size_t)n * C_] = f2bf((acc[j][r] + bias) * scl);
            }
        }
    } else {        // v : D[row=o'][col=n]
        int orow = ot * 64 + w * 16 + l15;   // 512..767
        const bf16x8* Arow = reinterpret_cast<const bf16x8*>(Wb + (size_t)orow * C_);
        #pragma unroll
        for (int kk = 0; kk < 8; kk++) {
            bf16x8 a = Arow[kk * 4 + g];
            #pragma unroll
            for (int j = 0; j < 4; j++) {
                int nrow = nt * 64 + j * 16 + l15;
                bf16x8 bfr = reinterpret_cast<const bf16x8*>(hTb + (size_t)nrow * C_)[kk * 4 + g];
                acc[j] = mfma16(a, bfr, acc[j]);
            }
        }
        #pragma unroll
        for (int j = 0; j < 4; j++) {
            #pragma unroll
            for (int r = 0; r < 4; r++) {
                int o = ot * 64 + w * 16 + g * 4 + r;
                int n = nt * 64 + j * 16 + l15;
                vO[(size_t)b * C_ * N_ + (size_t)(o - 512) * N_ + n] = f2bf(acc[j][r] + qkvb[o]);
            }
        }
    }
}

// ---------------- Flash attention: 8 waves, 4-way key split ----------------
// 512 thr: rg = w&1 (rows nb..nb+32), quarter q = w>>1 (key tiles q*32+t).
// Per quarter single-buffered chunk-major LDS (conflict-free, r11-verified):
//   Kt[q]: [32 chunk16B][32 key][8 ch]   Vt[q]: [4 chunk16B][256 ch][8 key]
// Iter: QK(t) -> bar -> issue stageK(t+1) -> softmax+PV(t) -> bar (K drain
// covered by PV) -> issue stageV(t+1) -> bar (V drain exposed).
// __launch_bounds__(512,1): 1 block/CU -> 2 waves/EU -> 256-VGPR budget
// (live ~240, no spill). Epilogue: 3-phase LDS quarter-sum tree.
__global__ __launch_bounds__(512, 1)
void attn_kernel(
        const uint16_t* __restrict__ qT, const uint16_t* __restrict__ kT,
        const uint16_t* __restrict__ vO, uint16_t* __restrict__ h2T) {
    int blk = blockIdx.x;
    int xx = blk & 7;
    int b  = xx >> 1;
    int qt = (blk >> 3) * 2 + (xx & 1);       // 0..63
    int lane = threadIdx.x & 63, w = threadIdx.x >> 6;   // w in 0..7
    int rg = w & 1, q = w >> 1;               // rowgroup, key-quarter
    int l31 = lane & 31, g5 = lane >> 5;
    const uint16_t* qTb = qT + (size_t)b * N_ * C_;
    const uint16_t* kTb = kT + (size_t)b * N_ * C_;
    const uint16_t* vb  = vO + (size_t)b * C_ * N_;
    int nb = qt * 64 + rg * 32;

    __shared__ __align__(16) char smem[151552];
    uint16_t* Ktp = reinterpret_cast<uint16_t*>(smem) + q * 8192;           // 16 KB/q
    uint16_t* Vtp = reinterpret_cast<uint16_t*>(smem + 65536) + q * 8192;   // 16 KB/q
    uint16_t* plw = reinterpret_cast<uint16_t*>(smem + 131072) + w * 1280;  // [32][40]

    // Q fragments: A[row=l31][k=s*16 + g5*8 + j]
    bf16x8 afr[16];
    {
        const uint16_t* qrow = qTb + (size_t)(nb + l31) * C_;
        #pragma unroll
        for (int s = 0; s < 16; s++)
            afr[s] = *reinterpret_cast<const bf16x8*>(qrow + s * 16 + g5 * 8);
    }

    f32x16 acc[8];
    #pragma unroll
    for (int i = 0; i < 8; i++) acc[i] = (f32x16){};
    float lsum[16];
    #pragma unroll
    for (int i = 0; i < 16; i++) lsum[i] = 0.f;

    // wave (rg,q) stages its half of quarter q's tiles (linear dests)
    auto stageK = [&](int mb) {
        #pragma unroll
        for (int i = 0; i < 8; i++) {         // K: 2 chunk-cols x 32 keys / instr
            int c2 = rg * 16 + i * 2;
            gload16(kTb + (size_t)(mb + l31) * C_ + (c2 + g5) * 8, Ktp + c2 * 256);
        }
    };
    auto stageV = [&](int mb) {
        #pragma unroll
        for (int i = 0; i < 8; i++) {         // V: 1 chunk x 64 ch / instr
            int c   = i >> 1;
            int cb3 = rg * 128 + (i & 1) * 64;
            gload16(vb + (size_t)(cb3 + lane) * N_ + mb + c * 8, Vtp + c * 2048 + cb3 * 8);
        }
    };

    stageK(q * 32 * KVB);
    stageV(q * 32 * KVB);
    __syncthreads();

    for (int mt = 0; mt < 32; mt++) {
        int nmb = (q * 32 + mt + 1) * KVB;

        // ---- QK^T: single accumulator chain (register-budget-safe) ----
        f32x16 sc = (f32x16){};
        #pragma unroll
        for (int s = 0; s < 16; s++) {
            bf16x8 kfr = *reinterpret_cast<const bf16x8*>(Ktp + (s * 2 + g5) * 256 + l31 * 8);
            sc = mfma32(afr[s], kfr, sc);
        }

        __syncthreads();                       // all waves done reading K(t)
        if (mt + 1 < 32) stageK(nmb);          // async; drains at next barrier,
                                               // covered by softmax+PV below
        // ---- static-max softmax ----
        #pragma unroll
        for (int reg = 0; reg < 16; reg++) {
            float p = __expf(sc[reg]);
            lsum[reg] += p;
            int row = (reg & 3) + 8 * (reg >> 2) + 4 * g5;
            plw[row * 40 + l31] = f2bf(p);
        }

        bf16x8 pf0 = *reinterpret_cast<const bf16x8*>(plw + l31 * 40 + g5 * 8);
        bf16x8 pf1 = *reinterpret_cast<const bf16x8*>(plw + l31 * 40 + 16 + g5 * 8);

        // ---- PV: 8 indep chains ----
        #pragma unroll
        for (int ct = 0; ct < 8; ct++) {
            int ch8 = (ct * 32 + l31) * 8;
            bf16x8 v0 = *reinterpret_cast<const bf16x8*>(Vtp + g5 * 2048 + ch8);
            bf16x8 v1 = *reinterpret_cast<const bf16x8*>(Vtp + (2 + g5) * 2048 + ch8);
            acc[ct] = mfma32(v0, pf0, acc[ct]);
            acc[ct] = mfma32(v1, pf1, acc[ct]);
        }

        __syncthreads();                       // all waves done reading V(t);
                                               // own K(t+1) loads drained here
        if (mt + 1 < 32) stageV(nmb);
        __syncthreads();                       // V(t+1) drained; tiles ready
    }

    // ---- lsum reduce (32-lane groups) -> lbuf ----
    #pragma unroll
    for (int d = 1; d < 32; d <<= 1) {
        #pragma unroll
        for (int reg = 0; reg < 16; reg++) lsum[reg] += __shfl_xor(lsum[reg], d);
    }
    float* Oset0 = reinterpret_cast<float*>(smem);             // [2rg][32][260] f32
    float* Oset1 = reinterpret_cast<float*>(smem + 66560);
    float* lbuf  = reinterpret_cast<float*>(smem + 133120);    // [4q][2rg][32]
    if ((lane & 31) == 0) {
        #pragma unroll
        for (int reg = 0; reg < 16; reg++) {
            int row = (reg & 3) + 8 * (reg >> 2) + 4 * g5;
            lbuf[(q * 2 + rg) * 32 + row] = lsum[reg];
        }
    }
    // ---- 3-phase quarter-sum tree: (1,3) write; (0,2) add; 2 writes; 0 adds ----
    auto owrite = [&](float* Os) {
        #pragma unroll
        for (int ct = 0; ct < 8; ct++) {
            #pragma unroll
            for (int qd = 0; qd < 4; qd++) {
                f32x4 v = {acc[ct][qd * 4 + 0], acc[ct][qd * 4 + 1],
                           acc[ct][qd * 4 + 2], acc[ct][qd * 4 + 3]};
                *reinterpret_cast<f32x4*>(
                    &Os[(size_t)(rg * 32 + l31) * 260 + ct * 32 + qd * 8 + 4 * g5]) = v;
            }
        }
    };
    auto oadd = [&](const float* Os) {
        #pragma unroll
        for (int ct = 0; ct < 8; ct++) {
            #pragma unroll
            for (int qd = 0; qd < 4; qd++) {
                f32x4 v = *reinterpret_cast<const f32x4*>(
                    &Os[(size_t)(rg * 32 + l31) * 260 + ct * 32 + qd * 8 + 4 * g5]);
                acc[ct][qd * 4 + 0] += v[0]; acc[ct][qd * 4 + 1] += v[1];
                acc[ct][qd * 4 + 2] += v[2]; acc[ct][qd * 4 + 3] += v[3];
            }
        }
    };
    if (q == 1) owrite(Oset0);
    if (q == 3) owrite(Oset1);
    __syncthreads();
    if (q == 0) oadd(Oset0);
    if (q == 2) oadd(Oset1);
    __syncthreads();
    if (q == 2) owrite(Oset0);
    __syncthreads();
    if (q == 0) {
        oadd(Oset0);
        float lt = lbuf[rg * 32 + l31] + lbuf[(2 + rg) * 32 + l31] +
                   lbuf[(4 + rg) * 32 + l31] + lbuf[(6 + rg) * 32 + l31];
        float inv = 1.0f / lt;
        uint16_t* rowp = h2T + ((size_t)b * N_ + nb + l31) * C_;
        #pragma unroll
        for (int ct = 0; ct < 8; ct++) {
            #pragma unroll
            for (int qd = 0; qd < 4; qd++) {
                uint32_t lo = f2bf(acc[ct][qd * 4 + 0] * inv) |
                              ((uint32_t)f2bf(acc[ct][qd * 4 + 1] * inv) << 16);
                uint32_t hi = f2bf(acc[ct][qd * 4 + 2] * inv) |
                              ((uint32_t)f2bf(acc[ct][qd * 4 + 3] * inv) << 16);
                uint2 val = {lo, hi};
                *reinterpret_cast<uint2*>(rowp + ct * 32 + qd * 8 + 4 * g5) = val;
            }
        }
    }
}

// ---------------- proj GEMM + bias + residual ----------------
__global__ __launch_bounds__(256) void proj_gemm(
        const uint16_t* __restrict__ Pwb, const float* __restrict__ pb,
        const uint16_t* __restrict__ h2T, const float* __restrict__ x,
        float* __restrict__ out) {
    int nt = blockIdx.x, ct = blockIdx.y, b = blockIdx.z;
    int lane = threadIdx.x & 63, w = threadIdx.x >> 6;
    int l15 = lane & 15, g = lane >> 4;
    const uint16_t* h2Tb = h2T + (size_t)b * N_ * C_;
    f32x4 z = {0.f, 0.f, 0.f, 0.f};
    f32x4 acc[4] = {z, z, z, z};
    int crow = ct * 64 + w * 16 + l15;
    const bf16x8* Arow = reinterpret_cast<const bf16x8*>(Pwb + (size_t)crow * C_);
    #pragma unroll
    for (int kk = 0; kk < 8; kk++) {
        bf16x8 a = Arow[kk * 4 + g];
        #pragma unroll
        for (int j = 0; j < 4; j++) {
            bf16x8 bfr = reinterpret_cast<const bf16x8*>(
                h2Tb + (size_t)(nt * 64 + j * 16 + l15) * C_)[kk * 4 + g];
            acc[j] = mfma16(a, bfr, acc[j]);
        }
    }
    #pragma unroll
    for (int j = 0; j < 4; j++) {
        #pragma unroll
        for (int r = 0; r < 4; r++) {
            int c = ct * 64 + w * 16 + g * 4 + r;
            int n = nt * 64 + j * 16 + l15;
            size_t idx = ((size_t)b * C_ + c) * N_ + n;
            out[idx] = x[idx] + acc[j][r] + pb[c];
        }
    }
}

extern "C" void kernel_launch(void* const* d_in, const int* in_sizes, int n_in,
                              void* d_out, int out_size, void* d_ws, size_t ws_size,
                              hipStream_t stream) {
    const float* x      = (const float*)d_in[0];
    const float* gn_w   = (const float*)d_in[1];
    const float* gn_b   = (const float*)d_in[2];
    const float* qkv_w  = (const float*)d_in[3];
    const float* qkv_b  = (const float*)d_in[4];
    const float* proj_w = (const float*)d_in[5];
    const float* proj_b = (const float*)d_in[6];
    float* out = (float*)d_out;

    char* ws = (char*)d_ws;
    float*    stats  = (float*)(ws);                          // 256 B
    float2*   part   = (float2*)(ws + 8192);                  // 8 KB
    uint16_t* qkvwb  = (uint16_t*)(ws + 65536);               // 384 KB
    uint16_t* projwb = (uint16_t*)(ws + 65536 + 768 * 256 * 2);
    uint16_t* hT     = (uint16_t*)(ws + (size_t)(1)  * (1 << 20));  // 8 MB [B][N][C]
    uint16_t* qT     = (uint16_t*)(ws + (size_t)(9)  * (1 << 20));  // 8 MB [B][N][C]
    uint16_t* kT     = (uint16_t*)(ws + (size_t)(17) * (1 << 20));  // 8 MB [B][N][C]
    uint16_t* vO     = (uint16_t*)(ws + (size_t)(25) * (1 << 20));  // 8 MB [B][C][N]
    uint16_t* h2T    = (uint16_t*)(ws + (size_t)(33) * (1 << 20));  // 8 MB [B][N][C]

    cast_weights<<<dim3(1024), dim3(256), 0, stream>>>(qkv_w, proj_w, qkvwb, projwb);
    gn_stats1<<<dim3(1024), dim3(256), 0, stream>>>(x, part);
    gn_stats2<<<dim3(1), dim3(1024), 0, stream>>>(part, stats);
    gn_apply<<<dim3(64, 4, 4), dim3(256), 0, stream>>>(x, gn_w, gn_b, stats, hT);
    qkv_gemm<<<dim3(64, 12, 4), dim3(256), 0, stream>>>(qkvwb, qkv_b, hT, qT, kT, vO);
    attn_kernel<<<dim3(256), dim3(512), 0, stream>>>(qT, kT, vO, h2T);
    proj_gemm<<<dim3(64, 4, 4), dim3(256), 0, stream>>>(projwb, proj_b, h2T, x, out);
}

// Round 17
// 221.668 us; speedup vs baseline: 2.1051x; 1.5183x over previous
//
#include <hip/hip_runtime.h>
#include <stdint.h>

// AttentionBlock: GN -> QKV -> softmax(QK^T/sqrt(C)) V -> proj + residual
// B=4, C=256, H=W=64, N=4096, groups=8 (32 ch/group)
// All matmuls bf16 MFMA (fp32 accumulate). fp32 threshold 0.1 absmax.
//
// Round 17: consolidation. attn reverted to the round-10 kernel VERBATIM
// (best measured: 131us; 8 waves = 2/SIMD, 2-way key split, double-buffered
// K/V LDS, ONE barrier/iter — every structural variant since regressed).
// qkv_gemm epilogue rewritten: 64x64 output tiles bounce through a padded
// LDS tile (pitch 68) and store as coalesced 16B chunks, replacing 12.6M
// scalar 2B scatter stores.

#define B_ 4
#define C_ 256
#define N_ 4096
#define KVB 32

using bf16x8 = __attribute__((ext_vector_type(8))) __bf16;
using f32x4  = __attribute__((ext_vector_type(4))) float;

__device__ __forceinline__ uint16_t f2bf(float f) {
    uint32_t u = __float_as_uint(f);
    u = (u + 0x7fffu + ((u >> 16) & 1u)) >> 16;   // RNE
    return (uint16_t)u;
}

__device__ __forceinline__ f32x4 mfma16(bf16x8 a, bf16x8 b, f32x4 c) {
    return __builtin_amdgcn_mfma_f32_16x16x32_bf16(a, b, c, 0, 0, 0);
}

__device__ __forceinline__ void gload16(const void* g, void* l) {
    __builtin_amdgcn_global_load_lds(
        (const __attribute__((address_space(1))) uint32_t*)g,
        (__attribute__((address_space(3))) uint32_t*)l, 16, 0, 0);
}

// ---------------- cast weights to bf16 ----------------
__global__ __launch_bounds__(256) void cast_weights(
        const float* __restrict__ qkvw, const float* __restrict__ projw,
        uint16_t* __restrict__ qkvwb, uint16_t* __restrict__ projwb) {
    int i = blockIdx.x * 256 + threadIdx.x;
    if (i < 768 * 256) qkvwb[i] = f2bf(qkvw[i]);
    int j = i - 768 * 256;
    if (j >= 0 && j < 256 * 256) projwb[j] = f2bf(projw[j]);
}

// ---------------- GroupNorm stats, two-stage ----------------
__global__ __launch_bounds__(256) void gn_stats1(const float* __restrict__ x,
                                                 float2* __restrict__ part) {
    int i = blockIdx.x;
    const float4* p = reinterpret_cast<const float4*>(x + (size_t)i * 4096);
    float s = 0.f, ss = 0.f;
    #pragma unroll
    for (int j = 0; j < 4; j++) {
        float4 v = p[threadIdx.x + j * 256];
        s  += v.x + v.y + v.z + v.w;
        ss += v.x*v.x + v.y*v.y + v.z*v.z + v.w*v.w;
    }
    #pragma unroll
    for (int d = 32; d > 0; d >>= 1) { s += __shfl_down(s, d); ss += __shfl_down(ss, d); }
    __shared__ float rs[4], rss[4];
    int wid = threadIdx.x >> 6;
    if ((threadIdx.x & 63) == 0) { rs[wid] = s; rss[wid] = ss; }
    __syncthreads();
    if (threadIdx.x == 0) {
        float2 o;
        o.x = rs[0] + rs[1] + rs[2] + rs[3];
        o.y = rss[0] + rss[1] + rss[2] + rss[3];
        part[i] = o;
    }
}
__global__ __launch_bounds__(1024) void gn_stats2(const float2* __restrict__ part,
                                                  float* __restrict__ stats) {
    int t = threadIdx.x;
    int g = t >> 5, j = t & 31;
    float2 v = part[g * 32 + j];
    float s = v.x, ss = v.y;
    #pragma unroll
    for (int d = 16; d > 0; d >>= 1) { s += __shfl_xor(s, d); ss += __shfl_xor(ss, d); }
    if (j == 0) {
        float mean = s / 131072.f;
        float var  = ss / 131072.f - mean * mean;
        stats[g * 2]     = mean;
        stats[g * 2 + 1] = rsqrtf(var + 1e-5f);
    }
}

// ---------------- GN apply + transpose: hT[b][n][c] bf16 ----------------
__global__ __launch_bounds__(256) void gn_apply(
        const float* __restrict__ x, const float* __restrict__ gnw,
        const float* __restrict__ gnb, const float* __restrict__ stats,
        uint16_t* __restrict__ hT) {
    int nb = blockIdx.x * 64, cb = blockIdx.y * 64, b = blockIdx.z;
    __shared__ uint16_t lds[64][64];          // [n][c]
    int t = threadIdx.x;
    int c_l = t >> 4;
    int n4  = (t & 15) * 4;
    #pragma unroll
    for (int i = 0; i < 4; i++) {
        int c = cb + c_l + 16 * i;
        int sg = b * 8 + (c >> 5);
        float mean = stats[sg * 2], rstd = stats[sg * 2 + 1];
        float sc = gnw[c] * rstd;
        float sh = gnb[c] - mean * sc;
        float4 v = *reinterpret_cast<const float4*>(x + ((size_t)b * C_ + c) * N_ + nb + n4);
        lds[n4 + 0][c_l + 16 * i] = f2bf(fmaf(v.x, sc, sh));
        lds[n4 + 1][c_l + 16 * i] = f2bf(fmaf(v.y, sc, sh));
        lds[n4 + 2][c_l + 16 * i] = f2bf(fmaf(v.z, sc, sh));
        lds[n4 + 3][c_l + 16 * i] = f2bf(fmaf(v.w, sc, sh));
    }
    __syncthreads();
    int n_l = t >> 2, c16 = (t & 3) * 16;
    uint4* dst = reinterpret_cast<uint4*>(hT + ((size_t)b * N_ + nb + n_l) * C_ + cb + c16);
    const uint4* sp = reinterpret_cast<const uint4*>(&lds[n_l][c16]);
    dst[0] = sp[0]; dst[1] = sp[1];
}

// ---------------- QKV GEMM (coalesced stores via LDS tile) ----------------
// q,k transposed [n][o]; q pre-scaled by 1/16. v kept [o'][n].
// Output tile (64x64) bounced through LDS (pitch 68 u16) -> 16B stores.
__global__ __launch_bounds__(256) void qkv_gemm(
        const uint16_t* __restrict__ Wb, const float* __restrict__ qkvb,
        const uint16_t* __restrict__ hT, uint16_t* __restrict__ qT,
        uint16_t* __restrict__ kT, uint16_t* __restrict__ vO) {
    int nt = blockIdx.x, ot = blockIdx.y, b = blockIdx.z;
    int lane = threadIdx.x & 63, w = threadIdx.x >> 6;
    int l15 = lane & 15, g = lane >> 4;
    const uint16_t* hTb = hT + (size_t)b * N_ * C_;
    f32x4 z = {0.f, 0.f, 0.f, 0.f};
    f32x4 acc[4] = {z, z, z, z};
    __shared__ uint16_t tile[64 * 68];        // 8.5 KB, pitch 68 (bank-safe)

    if (ot < 8) {   // q,k : D[row=n][col=o]; tile[n_local][o_local]
        int nrow = nt * 64 + w * 16 + l15;
        const bf16x8* Arow = reinterpret_cast<const bf16x8*>(hTb + (size_t)nrow * C_);
        #pragma unroll
        for (int kk = 0; kk < 8; kk++) {
            bf16x8 a = Arow[kk * 4 + g];
            #pragma unroll
            for (int j = 0; j < 4; j++) {
                int orow = ot * 64 + j * 16 + l15;
                bf16x8 bfr = reinterpret_cast<const bf16x8*>(Wb + (size_t)orow * C_)[kk * 4 + g];
                acc[j] = mfma16(a, bfr, acc[j]);
            }
        }
        bool isq = (ot < 4);
        float scl = isq ? 0.0625f : 1.0f;
        #pragma unroll
        for (int j = 0; j < 4; j++) {
            int o = ot * 64 + j * 16 + l15;
            float bias = qkvb[o];
            #pragma unroll
            for (int r = 0; r < 4; r++)
                tile[(w * 16 + g * 4 + r) * 68 + j * 16 + l15] =
                    f2bf((acc[j][r] + bias) * scl);
        }
        __syncthreads();
        uint16_t* dstb = isq ? (qT + (size_t)b * N_ * C_ + ot * 64)
                             : (kT + (size_t)b * N_ * C_ + (ot - 4) * 64);
        int t = threadIdx.x;
        #pragma unroll
        for (int i = 0; i < 2; i++) {
            int idx = i * 256 + t;
            int row = idx >> 3, cc = (idx & 7) * 8;
            uint4 val = *reinterpret_cast<const uint4*>(&tile[row * 68 + cc]);
            *reinterpret_cast<uint4*>(dstb + (size_t)(nt * 64 + row) * C_ + cc) = val;
        }
    } else {        // v : D[row=o'][col=n]; tile[o_local][n_local]
        int orow = ot * 64 + w * 16 + l15;   // 512..767
        const bf16x8* Arow = reinterpret_cast<const bf16x8*>(Wb + (size_t)orow * C_);
        #pragma unroll
        for (int kk = 0; kk < 8; kk++) {
            bf16x8 a = Arow[kk * 4 + g];
            #pragma unroll
            for (int j = 0; j < 4; j++) {
                int nrow = nt * 64 + j * 16 + l15;
                bf16x8 bfr = reinterpret_cast<const bf16x8*>(hTb + (size_t)nrow * C_)[kk * 4 + g];
                acc[j] = mfma16(a, bfr, acc[j]);
            }
        }
        #pragma unroll
        for (int j = 0; j < 4; j++) {
            #pragma unroll
            for (int r = 0; r < 4; r++) {
                int o = ot * 64 + w * 16 + g * 4 + r;
                tile[(w * 16 + g * 4 + r) * 68 + j * 16 + l15] =
                    f2bf(acc[j][r] + qkvb[o]);
            }
        }
        __syncthreads();
        uint16_t* dstb = vO + (size_t)b * C_ * N_ + (size_t)(ot - 8) * 64 * N_;
        int t = threadIdx.x;
        #pragma unroll
        for (int i = 0; i < 2; i++) {
            int idx = i * 256 + t;
            int row = idx >> 3, cc = (idx & 7) * 8;
            uint4 val = *reinterpret_cast<const uint4*>(&tile[row * 68 + cc]);
            *reinterpret_cast<uint4*>(dstb + (size_t)row * N_ + nt * 64 + cc) = val;
        }
    }
}

// ---------------- Flash attention: 8 waves, 2-way key split (round 10) -----
// Block: 512 thr = 8 waves. Wave w: rowgroup rg = w&3 (rows nb+rg*16),
// key half h = w>>2 (tiles h*64+i, i=0..63). Per-half double-buffered K/V in
// LDS (Kt/Vt[2][half]); 64 iterations; ONE barrier per iter.
// Static-max softmax (m=0, q pre-scaled): p=exp(s), per-lane l partials.
// Epilogue: half 1 writes (O,l) to LDS (Kt region reused as fp32), half 0
// merges (O0+O1, l0+l1), normalizes, stores h2T[n][c].
//   K tile [32 r][32 chunk16B], chunk' = chunk ^ (r&7)
//   V tile [256 ch][4 chunk16B], chunk' = chunk ^ ((ch>>1)&3)
//   plds rows padded to 40 u16
__global__ __launch_bounds__(512, 2) void attn_kernel(
        const uint16_t* __restrict__ qT, const uint16_t* __restrict__ kT,
        const uint16_t* __restrict__ vO, uint16_t* __restrict__ h2T) {
    int blk = blockIdx.x;
    int xx = blk & 7;
    int b  = xx >> 1;
    int qt = (blk >> 3) * 2 + (xx & 1);       // 0..63
    int lane = threadIdx.x & 63, w = threadIdx.x >> 6;   // w in 0..7
    int rg = w & 3, h = w >> 2;
    int l15 = lane & 15, g = lane >> 4;
    const uint16_t* qTb = qT + (size_t)b * N_ * C_;
    const uint16_t* kTb = kT + (size_t)b * N_ * C_;
    const uint16_t* vb  = vO + (size_t)b * C_ * N_;
    int nb = qt * 64 + rg * 16;

    __shared__ uint16_t Kt[2][2][32 * 256];   // [buf][half], 64 KB
    __shared__ uint16_t Vt[2][2][256 * 32];   // [buf][half], 64 KB
    __shared__ uint16_t plds[8][16][40];      // 10 KB, wave-private padded

    // Q fragments (once)
    bf16x8 afr[8];
    {
        const bf16x8* qrow = reinterpret_cast<const bf16x8*>(qTb + (size_t)(nb + l15) * C_);
        #pragma unroll
        for (int kk = 0; kk < 8; kk++) afr[kk] = qrow[kk * 4 + g];
    }

    f32x4 z = {0.f, 0.f, 0.f, 0.f};
    f32x4 acc[16];
    #pragma unroll
    for (int i = 0; i < 16; i++) acc[i] = z;
    float l_r[4] = {0.f, 0.f, 0.f, 0.f};

    // wave w stages its half's next tile: K rows rg*8..+8, V ch rg*64..+64
    auto stage = [&](int buf, int mb) {
        #pragma unroll
        for (int i = 0; i < 4; i++) {
            int rb = rg * 8 + i * 2;
            int r  = rb + (lane >> 5);
            int c  = (lane & 31) ^ (r & 7);
            gload16(kTb + (size_t)(mb + r) * C_ + c * 8, &Kt[buf][h][rb * 256]);
        }
        #pragma unroll
        for (int i = 0; i < 4; i++) {
            int cb2 = rg * 64 + i * 16;
            int ch = cb2 + (lane >> 2);
            int c  = (lane & 3) ^ ((ch >> 1) & 3);
            gload16(vb + (size_t)ch * N_ + mb + c * 8, &Vt[buf][h][cb2 * 32]);
        }
    };

    stage(0, h * 64 * KVB);
    __syncthreads();

    for (int mt = 0; mt < 64; mt++) {
        int buf = mt & 1;
        if (mt + 1 < 64) stage(buf ^ 1, (h * 64 + mt + 1) * KVB);

        // ---- QK^T from this half's K tile ----
        f32x4 sc0 = z, sc1 = z;
        #pragma unroll
        for (int kk = 0; kk < 8; kk++) {
            int c0 = (kk * 4 + g) ^ (l15 & 7);
            bf16x8 k0 = *reinterpret_cast<const bf16x8*>(&Kt[buf][h][l15 * 256 + c0 * 8]);
            bf16x8 k1 = *reinterpret_cast<const bf16x8*>(&Kt[buf][h][(16 + l15) * 256 + c0 * 8]);
            sc0 = mfma16(afr[kk], k0, sc0);
            sc1 = mfma16(afr[kk], k1, sc1);
        }

        // ---- static-max softmax ----
        #pragma unroll
        for (int r = 0; r < 4; r++) {
            float p0 = __expf(sc0[r]);
            float p1 = __expf(sc1[r]);
            l_r[r] += p0 + p1;
            plds[w][g * 4 + r][l15]      = f2bf(p0);
            plds[w][g * 4 + r][16 + l15] = f2bf(p1);
        }
        // plds wave-private: no barrier needed

        bf16x8 pb = *reinterpret_cast<const bf16x8*>(&plds[w][l15][g * 8]);

        // ---- PV from this half's V tile ----
        #pragma unroll
        for (int ct = 0; ct < 16; ct++) {
            int ch = ct * 16 + l15;
            bf16x8 va = *reinterpret_cast<const bf16x8*>(
                &Vt[buf][h][ch * 32 + ((g ^ ((ch >> 1) & 3)) * 8)]);
            acc[ct] = mfma16(va, pb, acc[ct]);
        }

        __syncthreads();   // drains vmcnt; both halves advance together
    }

    // ---- reduce l partials within wave; map to per-lane q-row = l15 ----
    #pragma unroll
    for (int d = 1; d < 16; d <<= 1) {
        #pragma unroll
        for (int r = 0; r < 4; r++) l_r[r] += __shfl_xor(l_r[r], d);
    }
    int bsrc = (l15 >> 2) * 16;
    int sel = l15 & 3;
    float s0 = __shfl(l_r[0], bsrc), s1 = __shfl(l_r[1], bsrc),
          s2 = __shfl(l_r[2], bsrc), s3 = __shfl(l_r[3], bsrc);
    float lv = (sel == 0) ? s0 : (sel == 1) ? s1 : (sel == 2) ? s2 : s3;

    // ---- cross-half merge via LDS (reuse Kt as fp32 O-buffer, Vt for l) ----
    float* Olds = reinterpret_cast<float*>(&Kt[0][0][0]);   // [64 rows][256 ch] f32
    float* lbuf = reinterpret_cast<float*>(&Vt[0][0][0]);   // [64] f32
    if (h == 1) {
        if (lane < 16) lbuf[rg * 16 + l15] = lv;
        #pragma unroll
        for (int ct = 0; ct < 16; ct++)
            *reinterpret_cast<f32x4*>(&Olds[(size_t)(rg * 16 + l15) * 256 + ct * 16 + g * 4]) = acc[ct];
    }
    __syncthreads();
    if (h == 0) {
        float inv = 1.0f / (lv + lbuf[rg * 16 + l15]);
        uint16_t* row = h2T + ((size_t)b * N_ + nb + l15) * C_;
        #pragma unroll
        for (int ct = 0; ct < 16; ct++) {
            f32x4 o2 = *reinterpret_cast<const f32x4*>(
                &Olds[(size_t)(rg * 16 + l15) * 256 + ct * 16 + g * 4]);
            uint32_t lo = f2bf((acc[ct][0] + o2[0]) * inv) |
                          ((uint32_t)f2bf((acc[ct][1] + o2[1]) * inv) << 16);
            uint32_t hi = f2bf((acc[ct][2] + o2[2]) * inv) |
                          ((uint32_t)f2bf((acc[ct][3] + o2[3]) * inv) << 16);
            *reinterpret_cast<uint32_t*>(row + ct * 16 + g * 4)     = lo;
            *reinterpret_cast<uint32_t*>(row + ct * 16 + g * 4 + 2) = hi;
        }
    }
}

// ---------------- proj GEMM + bias + residual ----------------
__global__ __launch_bounds__(256) void proj_gemm(
        const uint16_t* __restrict__ Pwb, const float* __restrict__ pb,
        const uint16_t* __restrict__ h2T, const float* __restrict__ x,
        float* __restrict__ out) {
    int nt = blockIdx.x, ct = blockIdx.y, b = blockIdx.z;
    int lane = threadIdx.x & 63, w = threadIdx.x >> 6;
    int l15 = lane & 15, g = lane >> 4;
    const uint16_t* h2Tb = h2T + (size_t)b * N_ * C_;
    f32x4 z = {0.f, 0.f, 0.f, 0.f};
    f32x4 acc[4] = {z, z, z, z};
    int crow = ct * 64 + w * 16 + l15;
    const bf16x8* Arow = reinterpret_cast<const bf16x8*>(Pwb + (size_t)crow * C_);
    #pragma unroll
    for (int kk = 0; kk < 8; kk++) {
        bf16x8 a = Arow[kk * 4 + g];
        #pragma unroll
        for (int j = 0; j < 4; j++) {
            bf16x8 bfr = reinterpret_cast<const bf16x8*>(
                h2Tb + (size_t)(nt * 64 + j * 16 + l15) * C_)[kk * 4 + g];
            acc[j] = mfma16(a, bfr, acc[j]);
        }
    }
    #pragma unroll
    for (int j = 0; j < 4; j++) {
        #pragma unroll
        for (int r = 0; r < 4; r++) {
            int c = ct * 64 + w * 16 + g * 4 + r;
            int n = nt * 64 + j * 16 + l15;
            size_t idx = ((size_t)b * C_ + c) * N_ + n;
            out[idx] = x[idx] + acc[j][r] + pb[c];
        }
    }
}

extern "C" void kernel_launch(void* const* d_in, const int* in_sizes, int n_in,
                              void* d_out, int out_size, void* d_ws, size_t ws_size,
                              hipStream_t stream) {
    const float* x      = (const float*)d_in[0];
    const float* gn_w   = (const float*)d_in[1];
    const float* gn_b   = (const float*)d_in[2];
    const float* qkv_w  = (const float*)d_in[3];
    const float* qkv_b  = (const float*)d_in[4];
    const float* proj_w = (const float*)d_in[5];
    const float* proj_b = (const float*)d_in[6];
    float* out = (float*)d_out;

    char* ws = (char*)d_ws;
    float*    stats  = (float*)(ws);                          // 256 B
    float2*   part   = (float2*)(ws + 8192);                  // 8 KB
    uint16_t* qkvwb  = (uint16_t*)(ws + 65536);               // 384 KB
    uint16_t* projwb = (uint16_t*)(ws + 65536 + 768 * 256 * 2);
    uint16_t* hT     = (uint16_t*)(ws + (size_t)(1)  * (1 << 20));  // 8 MB [B][N][C]
    uint16_t* qT     = (uint16_t*)(ws + (size_t)(9)  * (1 << 20));  // 8 MB [B][N][C]
    uint16_t* kT     = (uint16_t*)(ws + (size_t)(17) * (1 << 20));  // 8 MB [B][N][C]
    uint16_t* vO     = (uint16_t*)(ws + (size_t)(25) * (1 << 20));  // 8 MB [B][C][N]
    uint16_t* h2T    = (uint16_t*)(ws + (size_t)(33) * (1 << 20));  // 8 MB [B][N][C]

    cast_weights<<<dim3(1024), dim3(256), 0, stream>>>(qkv_w, proj_w, qkvwb, projwb);
    gn_stats1<<<dim3(1024), dim3(256), 0, stream>>>(x, part);
    gn_stats2<<<dim3(1), dim3(1024), 0, stream>>>(part, stats);
    gn_apply<<<dim3(64, 4, 4), dim3(256), 0, stream>>>(x, gn_w, gn_b, stats, hT);
    qkv_gemm<<<dim3(64, 12, 4), dim3(256), 0, stream>>>(qkvwb, qkv_b, hT, qT, kT, vO);
    attn_kernel<<<dim3(256), dim3(512), 0, stream>>>(qT, kT, vO, h2T);
    proj_gemm<<<dim3(64, 4, 4), dim3(256), 0, stream>>>(projwb, proj_b, h2T, x, out);
}